// Round 4
// baseline (235.051 us; speedup 1.0000x reference)
//
#include <hip/hip_runtime.h>

#define NPTS 16384
#define NTHR 256
#define MPREP 32

#define WS_PACK   401408u
#define OFF_X2    401408u
#define OFF_H2    8790016u
#define WS_FULL   42344448u   // 392K pack + 8M X2 + 32M h2

typedef __attribute__((ext_vector_type(8))) short bf16x8;
typedef __attribute__((ext_vector_type(4))) float f32x4;

__device__ __forceinline__ unsigned short f2bf(float x) {
    unsigned u = __float_as_uint(x);
    return (unsigned short)((u + 0x7FFFu + ((u >> 16) & 1u)) >> 16);
}
__device__ __forceinline__ unsigned pk2(float a, float b) {
    return (unsigned)f2bf(a) | ((unsigned)f2bf(b) << 16);
}
__device__ __forceinline__ float bf2f(unsigned short h) {
    return __uint_as_float(((unsigned)h) << 16);
}
__device__ __forceinline__ float elu_f(float x) {
    return x > 0.f ? x : (__expf(x) - 1.f);
}

// Gather one 16x16x32 B-fragment directly from a row-major fp32 matrix W[K][N].
__device__ __forceinline__ bf16x8 load_bfrag(const float* __restrict__ W, int N,
                                             int kt, int nt, int lane) {
    int k0  = kt * 32 + ((lane >> 4) << 3);
    int col = nt * 16 + (lane & 15);
    const float* s = W + k0 * N + col;
    bf16x8 r;
#pragma unroll
    for (int j = 0; j < 8; j++) r[j] = (short)f2bf(s[j * N]);
    return r;
}

// ---------------- prep: pack w2 / wx1 / wx2 / wpw into bf16 B-fragments ----
// frag order: w2 [kt*4+nt] (8), wx1 [kt*16+nt] (128), wx2 (128), wpw [kt*8+nt] (128)
__global__ void pack_weights(const float* __restrict__ w2,
                             const float* __restrict__ wx1,
                             const float* __restrict__ wx2,
                             const float* __restrict__ wpw,
                             unsigned short* __restrict__ dst) {
    int gid  = blockIdx.x * 256 + threadIdx.x;   // 98*256 = 25088 = 392*64
    int frag = gid >> 6, lane = gid & 63;
    const float* src; int N, fl;
    if      (frag <   8) { src = w2;  N =  64; fl = frag;       }
    else if (frag < 136) { src = wx1; N = 256; fl = frag - 8;   }
    else if (frag < 264) { src = wx2; N = 256; fl = frag - 136; }
    else                 { src = wpw; N = 128; fl = frag - 264; }
    int NT  = N >> 4;
    int kt  = fl / NT, nt = fl - kt * NT;
    int k0  = kt * 32 + (lane >> 4) * 8;
    int col = nt * 16 + (lane & 15);
    const float* s = src + k0 * N + col;
    unsigned v[4];
#pragma unroll
    for (int u = 0; u < 4; u++) {
        unsigned lo = f2bf(s[(2 * u) * N]);
        unsigned hi = f2bf(s[(2 * u + 1) * N]);
        v[u] = lo | (hi << 16);
    }
    *(uint4*)&dst[gid * 8] = make_uint4(v[0], v[1], v[2], v[3]);
}

// ---------------- prep kernel: h2 + X-pipeline over 32-point blocks ----------
// Writes per point:
//   gH2[pt]: B-frag layout [4 nt][32 lane][8] u16  (2048 B/pt)
//   gX2[pt]: A-frag layout [32 lane][8] u16        ( 512 B/pt)
// LDS (43008 B -> 2-3 blocks/CU at 512 thr):
//   0     s_ptsl [32][48] f32   6144
//   6144  overlay (36864):
//         s_h1 [256][72] u16 36864   (B rounds only)
//         s_x0 [32][264] u16 16896   @6144   (C->D)
//         s_x1 [32][264] u16 16896   @23040  (D->E)
__global__ __launch_bounds__(512, 4)
void xprep(const float* __restrict__ rep_pt, const float* __restrict__ pts,
           const float* __restrict__ w1,  const float* __restrict__ b1,
           const float* __restrict__ b2,
           const float* __restrict__ wc1, const float* __restrict__ bc1,
           const float* __restrict__ bx1, const float* __restrict__ bx2,
           const unsigned short* __restrict__ wpack,
           unsigned short* __restrict__ gH2, unsigned short* __restrict__ gX2) {
    __shared__ __align__(16) char smem[43008];
    float*          s_ptsl = (float*)smem;                       // [32][48]
    unsigned short* s_h1   = (unsigned short*)(smem + 6144);     // [256][72]
    unsigned short* s_x0   = (unsigned short*)(smem + 6144);     // [32][264]
    unsigned short* s_x1   = (unsigned short*)(smem + 23040);    // [32][264]

    const int t    = threadIdx.x;
    const int lane = t & 63;
    const int w    = t >> 6;          // 0..7
    const int cl   = lane & 15;
    const int hh   = lane >> 4;
    const int gp0  = blockIdx.x * MPREP;

    // ---- A: pts_local -> LDS ----
    for (int idx = t; idx < MPREP * 48; idx += 512) {
        int m = idx / 48, r = idx - m * 48;
        int k = r / 3,    d = r - k * 3;
        int gp = gp0 + m;
        s_ptsl[idx] = pts[(gp * 16 + k) * 3 + d] - rep_pt[gp * 3 + d];
    }
    __syncthreads();

    // ---- B: h1 (VALU) + h2 (MFMA) -> gH2 frags, 2 rounds of 256 rows ----
    {
        const bf16x8* wp = (const bf16x8*)wpack;   // w2 frags
        bf16x8 Bf[8];
#pragma unroll
        for (int f = 0; f < 8; f++) Bf[f] = wp[f * 64 + lane];
        float bias[4];
#pragma unroll
        for (int nt = 0; nt < 4; nt++) bias[nt] = b2[nt * 16 + cl];

        for (int R = 0; R < 2; R++) {
            {   // h1: 2 threads per row, 32 channels each; 512 thr -> 256 rows
                int lr  = t >> 1;
                int row = 256 * R + lr;           // 0..511 = m*16+k
                int m = row >> 4, k = row & 15;
                float p0 = s_ptsl[m * 48 + k * 3 + 0];
                float p1 = s_ptsl[m * 48 + k * 3 + 1];
                float p2 = s_ptsl[m * 48 + k * 3 + 2];
                int cb = (t & 1) * 32;
#pragma unroll
                for (int cc = 0; cc < 4; cc++) {
                    unsigned v[4];
#pragma unroll
                    for (int u = 0; u < 4; u++) {
                        int c0 = cb + cc * 8 + u * 2;
                        float a  = fmaf(p0, w1[c0],     fmaf(p1, w1[64 + c0],     fmaf(p2, w1[128 + c0],     b1[c0])));
                        float bb = fmaf(p0, w1[c0 + 1], fmaf(p1, w1[64 + c0 + 1], fmaf(p2, w1[128 + c0 + 1], b1[c0 + 1])));
                        v[u] = pk2(elu_f(a), elu_f(bb));
                    }
                    *(uint4*)&s_h1[lr * 72 + cb + cc * 8] = make_uint4(v[0], v[1], v[2], v[3]);
                }
            }
            __syncthreads();
            {   // h2 MFMA: 16 row-tiles, 2 per wave; K=64, N=64
#pragma unroll
                for (int i = 0; i < 2; i++) {
                    int rtl  = w * 2 + i;             // 0..15
                    int mloc = R * 16 + rtl;          // 0..31
                    size_t gp = (size_t)(gp0 + mloc);
                    bf16x8 a0 = *(const bf16x8*)&s_h1[(rtl * 16 + cl) * 72 + 0  + hh * 8];
                    bf16x8 a1 = *(const bf16x8*)&s_h1[(rtl * 16 + cl) * 72 + 32 + hh * 8];
#pragma unroll
                    for (int nt = 0; nt < 4; nt++) {
                        f32x4 acc = {bias[nt], bias[nt], bias[nt], bias[nt]};
                        acc = __builtin_amdgcn_mfma_f32_16x16x32_bf16(a0, Bf[0 * 4 + nt], acc, 0, 0, 0);
                        acc = __builtin_amdgcn_mfma_f32_16x16x32_bf16(a1, Bf[1 * 4 + nt], acc, 0, 0, 0);
                        unsigned lo = pk2(elu_f(acc[0]), elu_f(acc[1]));
                        unsigned hi = pk2(elu_f(acc[2]), elu_f(acc[3]));
                        unsigned short* dp = &gH2[((gp * 4 + nt) * 32 + (hh >> 1) * 16 + cl) * 8 + (hh & 1) * 4];
                        *(uint2*)dp = make_uint2(lo, hi);
                    }
                }
            }
            __syncthreads();
        }
    }

    // ---- C: X0 = elu(ptsl einsum wc1 + bc1) (VALU) ----
    {
        const int o  = t & 255;
        const int mb = (t >> 8) * 16;
        float wreg[48];                       // wc1[o][d][k] -> wreg[d*16+k]
#pragma unroll
        for (int q = 0; q < 12; q++) {
            float4 wv = *(const float4*)&wc1[o * 48 + q * 4];
            wreg[q * 4 + 0] = wv.x; wreg[q * 4 + 1] = wv.y;
            wreg[q * 4 + 2] = wv.z; wreg[q * 4 + 3] = wv.w;
        }
        float bo = bc1[o];
#pragma unroll 1
        for (int ml = 0; ml < 16; ml++) {
            int m = mb + ml;
            float acc = bo;
#pragma unroll
            for (int q = 0; q < 12; q++) {
                float4 pv = *(const float4*)&s_ptsl[m * 48 + q * 4];   // flat f = k*3+d
                acc = fmaf(pv.x, wreg[((q * 4 + 0) % 3) * 16 + (q * 4 + 0) / 3], acc);
                acc = fmaf(pv.y, wreg[((q * 4 + 1) % 3) * 16 + (q * 4 + 1) / 3], acc);
                acc = fmaf(pv.z, wreg[((q * 4 + 2) % 3) * 16 + (q * 4 + 2) / 3], acc);
                acc = fmaf(pv.w, wreg[((q * 4 + 3) % 3) * 16 + (q * 4 + 3) / 3], acc);
            }
            s_x0[m * 264 + o] = f2bf(elu_f(acc));
        }
    }
    __syncthreads();

    // ---- D: X1 = elu(X0 @ wx1 + bx1), M=32,N=256,K=256; 2 nt/wave, 2 m-tiles ----
    {
        const bf16x8* wp = (const bf16x8*)wpack + 512;  // wx1
        f32x4 acc[2][2];
#pragma unroll
        for (int q = 0; q < 2; q++) {
            float bv = bx1[(w * 2 + q) * 16 + cl];
#pragma unroll
            for (int mt = 0; mt < 2; mt++) acc[mt][q] = (f32x4){bv, bv, bv, bv};
        }
#pragma unroll
        for (int kt = 0; kt < 8; kt++) {
            bf16x8 b0 = wp[(kt * 16 + w * 2 + 0) * 64 + lane];
            bf16x8 b1 = wp[(kt * 16 + w * 2 + 1) * 64 + lane];
#pragma unroll
            for (int mt = 0; mt < 2; mt++) {
                bf16x8 a = *(const bf16x8*)&s_x0[(mt * 16 + cl) * 264 + kt * 32 + hh * 8];
                acc[mt][0] = __builtin_amdgcn_mfma_f32_16x16x32_bf16(a, b0, acc[mt][0], 0, 0, 0);
                acc[mt][1] = __builtin_amdgcn_mfma_f32_16x16x32_bf16(a, b1, acc[mt][1], 0, 0, 0);
            }
        }
        __syncthreads();   // s_x0 region stays; s_x1 separate — barrier orders x1 write vs x0 read of other waves? x0/x1 disjoint, but keep for safety before overwrite-free write
#pragma unroll
        for (int q = 0; q < 2; q++) {
            int nt = w * 2 + q;
#pragma unroll
            for (int mt = 0; mt < 2; mt++) {
#pragma unroll
                for (int r = 0; r < 4; r++) {
                    int m = mt * 16 + hh * 4 + r;
                    s_x1[m * 264 + nt * 16 + cl] = f2bf(elu_f(acc[mt][q][r]));
                }
            }
        }
    }
    __syncthreads();

    // ---- E: X2 = X1 @ wx2 + bx2 (no act) -> gX2 A-frag layout ----
    {
        const bf16x8* wp = (const bf16x8*)wpack + 8704;  // wx2
        f32x4 acc[2][2];
#pragma unroll
        for (int q = 0; q < 2; q++) {
            float bv = bx2[(w * 2 + q) * 16 + cl];
#pragma unroll
            for (int mt = 0; mt < 2; mt++) acc[mt][q] = (f32x4){bv, bv, bv, bv};
        }
#pragma unroll
        for (int kt = 0; kt < 8; kt++) {
            bf16x8 b0 = wp[(kt * 16 + w * 2 + 0) * 64 + lane];
            bf16x8 b1 = wp[(kt * 16 + w * 2 + 1) * 64 + lane];
#pragma unroll
            for (int mt = 0; mt < 2; mt++) {
                bf16x8 a = *(const bf16x8*)&s_x1[(mt * 16 + cl) * 264 + kt * 32 + hh * 8];
                acc[mt][0] = __builtin_amdgcn_mfma_f32_16x16x32_bf16(a, b0, acc[mt][0], 0, 0, 0);
                acc[mt][1] = __builtin_amdgcn_mfma_f32_16x16x32_bf16(a, b1, acc[mt][1], 0, 0, 0);
            }
        }
        // X2 entry (point, i=nt, j=cl) -> A-frag lane (j>>3)*16+i, elem j&7
#pragma unroll
        for (int q = 0; q < 2; q++) {
            int ntE = w * 2 + q;
            int lp  = (cl >> 3) * 16 + ntE;
            int jj  = cl & 7;
#pragma unroll
            for (int mt = 0; mt < 2; mt++) {
#pragma unroll
                for (int r = 0; r < 4; r++) {
                    size_t gp = (size_t)(gp0 + mt * 16 + hh * 4 + r);
                    gX2[gp * 256 + lp * 8 + jj] = f2bf(acc[mt][q][r]);
                }
            }
        }
    }
}

// ---------------- main kernel: F (fts_X + depthwise) + G (pointwise+BN) ------
// 16 pts/block, 256 thr (4 waves), LDS = s_dw only (16640 B) -> 4 blocks/CU.
// Wave w handles channel groups cg = w*2, w*2+1 (cg<4: h2 half from gH2;
// cg>=4: fts half packed on the fly).
__global__ __launch_bounds__(NTHR, 4)
void xmain(const float* __restrict__ fts,
           const float* __restrict__ wdw, const float* __restrict__ bdw,
           const float* __restrict__ bpw,
           const float* __restrict__ bn_gamma, const float* __restrict__ bn_beta,
           const float* __restrict__ bn_mean,  const float* __restrict__ bn_var,
           const unsigned short* __restrict__ wpack,
           const unsigned short* __restrict__ gH2,
           const unsigned short* __restrict__ gX2,
           float* __restrict__ out) {
    __shared__ __align__(16) unsigned short s_dw[16 * 520];   // 16640 B

    const int t    = threadIdx.x;
    const int lane = t & 63;
    const int w    = t >> 6;          // 0..3
    const int cl   = lane & 15;
    const int hh   = lane >> 4;
    const int gp0  = blockIdx.x * 16;

    // ---- F ----
    {
        float wd[2][16];
        float4 bd[2];
#pragma unroll
        for (int g = 0; g < 2; g++) {
            int c = (w * 2 + g) * 16 + cl;    // 0..127
#pragma unroll
            for (int d = 0; d < 4; d++) {
                float4 v = *(const float4*)&wdw[c * 64 + d * 16 + 4 * hh];
                wd[g][d * 4 + 0] = v.x; wd[g][d * 4 + 1] = v.y;
                wd[g][d * 4 + 2] = v.z; wd[g][d * 4 + 3] = v.w;
            }
            bd[g] = *(const float4*)&bdw[c * 4];
        }

        auto LOADA = [&](int m) -> bf16x8 {
            bf16x8 a = {};
            if (lane < 32) a = *(const bf16x8*)&gX2[(size_t)(gp0 + m) * 256 + lane * 8];
            return a;
        };
        auto LOADB = [&](int m, int g) -> bf16x8 {
            bf16x8 b = {};
            int cg = w * 2 + g;
            if (lane < 32) {
                if (cg < 4) {
                    b = *(const bf16x8*)&gH2[(((size_t)(gp0 + m) * 4 + cg) * 32 + lane) * 8];
                } else {
                    const float* p = fts + ((size_t)(gp0 + m) * 16 + hh * 8) * 64 + (cg - 4) * 16 + cl;
                    union { bf16x8 v; uint4 u; } ub;
                    ub.u = make_uint4(pk2(p[0],   p[64]),  pk2(p[128], p[192]),
                                      pk2(p[256], p[320]), pk2(p[384], p[448]));
                    b = ub.v;
                }
            }
            return b;
        };

        bf16x8 a  = LOADA(0);
        bf16x8 b0 = LOADB(0, 0);
        bf16x8 b1 = LOADB(0, 1);
#pragma unroll
        for (int m = 0; m < 16; m++) {
            bf16x8 na = {}, nb0 = {}, nb1 = {};
            if (m < 15) {
                na  = LOADA(m + 1);
                nb0 = LOADB(m + 1, 0);
                nb1 = LOADB(m + 1, 1);
            }
#pragma unroll
            for (int g = 0; g < 2; g++) {
                f32x4 acc = {0.f, 0.f, 0.f, 0.f};
                acc = __builtin_amdgcn_mfma_f32_16x16x32_bf16(a, g ? b1 : b0, acc, 0, 0, 0);
                float o[4];
#pragma unroll
                for (int d = 0; d < 4; d++) {
                    float s = acc[0] * wd[g][d * 4 + 0];
                    s = fmaf(acc[1], wd[g][d * 4 + 1], s);
                    s = fmaf(acc[2], wd[g][d * 4 + 2], s);
                    s = fmaf(acc[3], wd[g][d * 4 + 3], s);
                    s += __shfl_xor(s, 16);
                    s += __shfl_xor(s, 32);
                    o[d] = s;
                }
                if (hh == 0) {
                    int c = (w * 2 + g) * 16 + cl;
                    float4 bdv = bd[g];
                    ushort4 v;
                    v.x = f2bf(o[0] + bdv.x); v.y = f2bf(o[1] + bdv.y);
                    v.z = f2bf(o[2] + bdv.z); v.w = f2bf(o[3] + bdv.w);
                    *(ushort4*)&s_dw[m * 520 + c * 4] = v;
                }
            }
            a = na; b0 = nb0; b1 = nb1;
        }
    }
    __syncthreads();

    // ---- G: y = BN(elu(dw @ wpw + bpw)), M=16,N=128,K=512; 2 nt/wave ----
    {
        const bf16x8* wp = (const bf16x8*)wpack + 16896;  // wpw
        f32x4 acc[2];
#pragma unroll
        for (int q = 0; q < 2; q++) {
            float bv = bpw[(w * 2 + q) * 16 + cl];
            acc[q] = (f32x4){bv, bv, bv, bv};
        }
#pragma unroll
        for (int kt = 0; kt < 16; kt++) {
            bf16x8 a = *(const bf16x8*)&s_dw[cl * 520 + kt * 32 + hh * 8];
#pragma unroll
            for (int q = 0; q < 2; q++) {
                bf16x8 b = wp[(kt * 8 + w * 2 + q) * 64 + lane];
                acc[q] = __builtin_amdgcn_mfma_f32_16x16x32_bf16(a, b, acc[q], 0, 0, 0);
            }
        }
#pragma unroll
        for (int q = 0; q < 2; q++) {
            int co = (w * 2 + q) * 16 + cl;
            float scale = bn_gamma[co] * rsqrtf(bn_var[co] + 1e-5f);
            float shift = bn_beta[co] - bn_mean[co] * scale;
#pragma unroll
            for (int r = 0; r < 4; r++) {
                int m = hh * 4 + r;
                out[(size_t)(gp0 + m) * 128 + co] = fmaf(elu_f(acc[q][r]), scale, shift);
            }
        }
    }
}

// ---------------- fallback: round-2 fused kernel (best prior bench) ----------
// MPB=16, 256 thr. LDS 60928 B. Used when workspace < WS_FULL.
template <bool PACKED>
__global__ __launch_bounds__(NTHR, 2)
void xconv_fused(const float* __restrict__ rep_pt, const float* __restrict__ pts,
                 const float* __restrict__ fts,
                 const float* __restrict__ w1,  const float* __restrict__ b1,
                 const float* __restrict__ w2,  const float* __restrict__ b2,
                 const float* __restrict__ wc1, const float* __restrict__ bc1,
                 const float* __restrict__ wx1, const float* __restrict__ bx1,
                 const float* __restrict__ wx2, const float* __restrict__ bx2,
                 const float* __restrict__ wdw, const float* __restrict__ bdw,
                 const float* __restrict__ wpw, const float* __restrict__ bpw,
                 const float* __restrict__ bn_gamma, const float* __restrict__ bn_beta,
                 const float* __restrict__ bn_mean,  const float* __restrict__ bn_var,
                 const unsigned short* __restrict__ wpack,
                 float* __restrict__ out) {
    __shared__ __align__(16) char smem[60928];
    float*          s_ptsl = (float*)smem;                          // [16][48]
    unsigned short* s_h2f  = (unsigned short*)(smem + 3072);        // [16][4][32][8]
    unsigned short* s_h1   = (unsigned short*)(smem + 35840);       // [128][72]
    unsigned short* s_x0   = (unsigned short*)(smem + 35840);       // [16][264]
    unsigned short* s_x2f  = (unsigned short*)(smem + 35840);       // [16][32][8]
    unsigned short* s_x1   = (unsigned short*)(smem + 44288);       // [16][264]
    unsigned short* s_dw   = (unsigned short*)(smem + 44288);       // [16][520]

    const int t    = threadIdx.x;
    const int lane = t & 63;
    const int w    = t >> 6;
    const int cl   = lane & 15;
    const int hh   = lane >> 4;
    const int gp0  = blockIdx.x * 16;

    for (int idx = t; idx < 16 * 48; idx += NTHR) {
        int m = idx / 48, r = idx - m * 48;
        int k = r / 3,    d = r - k * 3;
        int gp = gp0 + m;
        s_ptsl[idx] = pts[(gp * 16 + k) * 3 + d] - rep_pt[gp * 3 + d];
    }
    __syncthreads();

    {
        const bf16x8* wp = (const bf16x8*)wpack;
        bf16x8 Bf[8];
#pragma unroll
        for (int f = 0; f < 8; f++) {
            if (PACKED) Bf[f] = wp[f * 64 + lane];
            else        Bf[f] = load_bfrag(w2, 64, f >> 2, f & 3, lane);
        }
        float bias[4];
#pragma unroll
        for (int nt = 0; nt < 4; nt++) bias[nt] = b2[nt * 16 + cl];

        for (int R = 0; R < 2; R++) {
            {
                int lr  = t >> 1;
                int row = 128 * R + lr;
                int m = row >> 4, k = row & 15;
                float p0 = s_ptsl[m * 48 + k * 3 + 0];
                float p1 = s_ptsl[m * 48 + k * 3 + 1];
                float p2 = s_ptsl[m * 48 + k * 3 + 2];
                int cb = (t & 1) * 32;
#pragma unroll
                for (int cc = 0; cc < 4; cc++) {
                    unsigned v[4];
#pragma unroll
                    for (int u = 0; u < 4; u++) {
                        int c0 = cb + cc * 8 + u * 2;
                        float a  = fmaf(p0, w1[c0],     fmaf(p1, w1[64 + c0],     fmaf(p2, w1[128 + c0],     b1[c0])));
                        float bb = fmaf(p0, w1[c0 + 1], fmaf(p1, w1[64 + c0 + 1], fmaf(p2, w1[128 + c0 + 1], b1[c0 + 1])));
                        v[u] = pk2(elu_f(a), elu_f(bb));
                    }
                    *(uint4*)&s_h1[lr * 72 + cb + cc * 8] = make_uint4(v[0], v[1], v[2], v[3]);
                }
            }
            __syncthreads();
            {
#pragma unroll
                for (int i = 0; i < 2; i++) {
                    int rtl = w * 2 + i;
                    int m   = 8 * R + rtl;
                    bf16x8 a0 = *(const bf16x8*)&s_h1[(rtl * 16 + cl) * 72 + 0  + hh * 8];
                    bf16x8 a1 = *(const bf16x8*)&s_h1[(rtl * 16 + cl) * 72 + 32 + hh * 8];
#pragma unroll
                    for (int nt = 0; nt < 4; nt++) {
                        f32x4 acc = {bias[nt], bias[nt], bias[nt], bias[nt]};
                        acc = __builtin_amdgcn_mfma_f32_16x16x32_bf16(a0, Bf[0 * 4 + nt], acc, 0, 0, 0);
                        acc = __builtin_amdgcn_mfma_f32_16x16x32_bf16(a1, Bf[1 * 4 + nt], acc, 0, 0, 0);
                        unsigned lo = pk2(elu_f(acc[0]), elu_f(acc[1]));
                        unsigned hi = pk2(elu_f(acc[2]), elu_f(acc[3]));
                        unsigned short* dp = &s_h2f[(((m * 4 + nt) * 32) + (hh >> 1) * 16 + cl) * 8 + (hh & 1) * 4];
                        *(uint2*)dp = make_uint2(lo, hi);
                    }
                }
            }
            __syncthreads();
        }
    }

    {
        float wreg[48];
#pragma unroll
        for (int q = 0; q < 12; q++) {
            float4 wv = *(const float4*)&wc1[t * 48 + q * 4];
            wreg[q * 4 + 0] = wv.x; wreg[q * 4 + 1] = wv.y;
            wreg[q * 4 + 2] = wv.z; wreg[q * 4 + 3] = wv.w;
        }
        float bo = bc1[t];
#pragma unroll 1
        for (int m = 0; m < 16; m++) {
            float acc = bo;
#pragma unroll
            for (int q = 0; q < 12; q++) {
                float4 pv = *(const float4*)&s_ptsl[m * 48 + q * 4];
                acc = fmaf(pv.x, wreg[((q * 4 + 0) % 3) * 16 + (q * 4 + 0) / 3], acc);
                acc = fmaf(pv.y, wreg[((q * 4 + 1) % 3) * 16 + (q * 4 + 1) / 3], acc);
                acc = fmaf(pv.z, wreg[((q * 4 + 2) % 3) * 16 + (q * 4 + 2) / 3], acc);
                acc = fmaf(pv.w, wreg[((q * 4 + 3) % 3) * 16 + (q * 4 + 3) / 3], acc);
            }
            s_x0[m * 264 + t] = f2bf(elu_f(acc));
        }
    }
    __syncthreads();

    {
        const bf16x8* wp = (const bf16x8*)wpack + 512;
        f32x4 acc[4];
#pragma unroll
        for (int q = 0; q < 4; q++) {
            float bv = bx1[(w * 4 + q) * 16 + cl];
            acc[q] = (f32x4){bv, bv, bv, bv};
        }
#pragma unroll
        for (int kt = 0; kt < 8; kt++) {
            bf16x8 a = *(const bf16x8*)&s_x0[cl * 264 + kt * 32 + hh * 8];
#pragma unroll
            for (int q = 0; q < 4; q++) {
                int nt = w * 4 + q;
                bf16x8 b;
                if (PACKED) b = wp[(kt * 16 + nt) * 64 + lane];
                else        b = load_bfrag(wx1, 256, kt, nt, lane);
                acc[q] = __builtin_amdgcn_mfma_f32_16x16x32_bf16(a, b, acc[q], 0, 0, 0);
            }
        }
#pragma unroll
        for (int q = 0; q < 4; q++) {
            int nt = w * 4 + q;
#pragma unroll
            for (int r = 0; r < 4; r++) {
                int m = hh * 4 + r;
                s_x1[m * 264 + nt * 16 + cl] = f2bf(elu_f(acc[q][r]));
            }
        }
    }
    __syncthreads();

    {
        const bf16x8* wp = (const bf16x8*)wpack + 8704;
        f32x4 acc[4];
#pragma unroll
        for (int q = 0; q < 4; q++) {
            float bv = bx2[(w * 4 + q) * 16 + cl];
            acc[q] = (f32x4){bv, bv, bv, bv};
        }
#pragma unroll
        for (int kt = 0; kt < 8; kt++) {
            bf16x8 a = *(const bf16x8*)&s_x1[cl * 264 + kt * 32 + hh * 8];
#pragma unroll
            for (int q = 0; q < 4; q++) {
                int nt = w * 4 + q;
                bf16x8 b;
                if (PACKED) b = wp[(kt * 16 + nt) * 64 + lane];
                else        b = load_bfrag(wx2, 256, kt, nt, lane);
                acc[q] = __builtin_amdgcn_mfma_f32_16x16x32_bf16(a, b, acc[q], 0, 0, 0);
            }
        }
#pragma unroll
        for (int q = 0; q < 4; q++) {
            int ntE = w * 4 + q;
            int lp  = (cl >> 3) * 16 + ntE;
            int jj  = cl & 7;
#pragma unroll
            for (int r = 0; r < 4; r++) {
                int m = hh * 4 + r;
                s_x2f[(m * 32 + lp) * 8 + jj] = f2bf(acc[q][r]);
            }
        }
    }
    __syncthreads();

    {
        const int cA = w * 16 + cl;
        const int cB = 64 + w * 16 + cl;
        float wdA[16], wdB[16];
#pragma unroll
        for (int d = 0; d < 4; d++) {
            float4 va = *(const float4*)&wdw[cA * 64 + d * 16 + 4 * hh];
            wdA[d * 4 + 0] = va.x; wdA[d * 4 + 1] = va.y; wdA[d * 4 + 2] = va.z; wdA[d * 4 + 3] = va.w;
            float4 vb = *(const float4*)&wdw[cB * 64 + d * 16 + 4 * hh];
            wdB[d * 4 + 0] = vb.x; wdB[d * 4 + 1] = vb.y; wdB[d * 4 + 2] = vb.z; wdB[d * 4 + 3] = vb.w;
        }
        float4 bdA = *(const float4*)&bdw[cA * 4];
        float4 bdB = *(const float4*)&bdw[cB * 4];
        const float* ftsp = fts + (size_t)gp0 * 1024 + (w * 16 + cl);

        float f0[8], f1[8];
        auto LDF = [&](int m, float* f) {
            if (lane < 32) {
                const float* p = ftsp + (m * 16 + hh * 8) * 64;
#pragma unroll
                for (int j = 0; j < 8; j++) f[j] = p[j * 64];
            }
        };
        auto BODY = [&](int m, float* fc_, float* fn_) {
            if (m < 15) LDF(m + 1, fn_);
            bf16x8 a  = {};
            bf16x8 bh = {};
            if (lane < 32) {
                a  = *(const bf16x8*)&s_x2f[(m * 32 + lane) * 8];
                bh = *(const bf16x8*)&s_h2f[((m * 4 + w) * 32 + lane) * 8];
            }
            f32x4 accA = {0.f, 0.f, 0.f, 0.f};
            f32x4 accB = {0.f, 0.f, 0.f, 0.f};
            accA = __builtin_amdgcn_mfma_f32_16x16x32_bf16(a, bh, accA, 0, 0, 0);
            bf16x8 bf_ = {};
            if (lane < 32) {
                union { bf16x8 v; uint4 u; } ub;
                ub.u = make_uint4(pk2(fc_[0], fc_[1]), pk2(fc_[2], fc_[3]),
                                  pk2(fc_[4], fc_[5]), pk2(fc_[6], fc_[7]));
                bf_ = ub.v;
            }
            accB = __builtin_amdgcn_mfma_f32_16x16x32_bf16(a, bf_, accB, 0, 0, 0);
            float oA[4], oB[4];
#pragma unroll
            for (int d = 0; d < 4; d++) {
                float sA = accA[0] * wdA[d * 4 + 0];
                sA = fmaf(accA[1], wdA[d * 4 + 1], sA);
                sA = fmaf(accA[2], wdA[d * 4 + 2], sA);
                sA = fmaf(accA[3], wdA[d * 4 + 3], sA);
                sA += __shfl_xor(sA, 16);
                sA += __shfl_xor(sA, 32);
                oA[d] = sA;
                float sB = accB[0] * wdB[d * 4 + 0];
                sB = fmaf(accB[1], wdB[d * 4 + 1], sB);
                sB = fmaf(accB[2], wdB[d * 4 + 2], sB);
                sB = fmaf(accB[3], wdB[d * 4 + 3], sB);
                sB += __shfl_xor(sB, 16);
                sB += __shfl_xor(sB, 32);
                oB[d] = sB;
            }
            if (hh == 0) {
                ushort4 va, vb;
                va.x = f2bf(oA[0] + bdA.x); va.y = f2bf(oA[1] + bdA.y);
                va.z = f2bf(oA[2] + bdA.z); va.w = f2bf(oA[3] + bdA.w);
                vb.x = f2bf(oB[0] + bdB.x); vb.y = f2bf(oB[1] + bdB.y);
                vb.z = f2bf(oB[2] + bdB.z); vb.w = f2bf(oB[3] + bdB.w);
                *(ushort4*)&s_dw[m * 520 + cA * 4] = va;
                *(ushort4*)&s_dw[m * 520 + cB * 4] = vb;
            }
        };
        LDF(0, f0);
#pragma unroll
        for (int mm = 0; mm < 8; mm++) {
            BODY(2 * mm + 0, f0, f1);
            BODY(2 * mm + 1, f1, f0);
        }
    }
    __syncthreads();

    {
        const bf16x8* wp = (const bf16x8*)wpack + 16896;
        f32x4 acc[2];
#pragma unroll
        for (int q = 0; q < 2; q++) {
            float bv = bpw[(w * 2 + q) * 16 + cl];
            acc[q] = (f32x4){bv, bv, bv, bv};
        }
#pragma unroll
        for (int kt = 0; kt < 16; kt++) {
            bf16x8 a = *(const bf16x8*)&s_dw[cl * 520 + kt * 32 + hh * 8];
#pragma unroll
            for (int q = 0; q < 2; q++) {
                int nt = w * 2 + q;
                bf16x8 b;
                if (PACKED) b = wp[(kt * 8 + nt) * 64 + lane];
                else        b = load_bfrag(wpw, 128, kt, nt, lane);
                acc[q] = __builtin_amdgcn_mfma_f32_16x16x32_bf16(a, b, acc[q], 0, 0, 0);
            }
        }
#pragma unroll
        for (int q = 0; q < 2; q++) {
            int co = (w * 2 + q) * 16 + cl;
            float scale = bn_gamma[co] * rsqrtf(bn_var[co] + 1e-5f);
            float shift = bn_beta[co] - bn_mean[co] * scale;
#pragma unroll
            for (int r = 0; r < 4; r++) {
                int m = hh * 4 + r;
                out[(gp0 + m) * 128 + co] = fmaf(elu_f(acc[q][r]), scale, shift);
            }
        }
    }
}

extern "C" void kernel_launch(void* const* d_in, const int* in_sizes, int n_in,
                              void* d_out, int out_size, void* d_ws, size_t ws_size,
                              hipStream_t stream) {
    const float* rep_pt   = (const float*)d_in[0];
    const float* pts      = (const float*)d_in[1];
    const float* fts      = (const float*)d_in[2];
    const float* w1       = (const float*)d_in[3];
    const float* b1       = (const float*)d_in[4];
    const float* w2       = (const float*)d_in[5];
    const float* b2       = (const float*)d_in[6];
    const float* wc1      = (const float*)d_in[7];
    const float* bc1      = (const float*)d_in[8];
    const float* wx1      = (const float*)d_in[9];
    const float* bx1      = (const float*)d_in[10];
    const float* wx2      = (const float*)d_in[11];
    const float* bx2      = (const float*)d_in[12];
    const float* wdw      = (const float*)d_in[13];
    const float* bdw      = (const float*)d_in[14];
    const float* wpw      = (const float*)d_in[15];
    const float* bpw      = (const float*)d_in[16];
    const float* bn_gamma = (const float*)d_in[17];
    const float* bn_beta  = (const float*)d_in[18];
    const float* bn_mean  = (const float*)d_in[19];
    const float* bn_var   = (const float*)d_in[20];
    float* out = (float*)d_out;

    unsigned short* wpack = (unsigned short*)d_ws;

    if (d_ws != nullptr && ws_size >= (size_t)WS_FULL) {
        unsigned short* gX2 = (unsigned short*)((char*)d_ws + OFF_X2);
        unsigned short* gH2 = (unsigned short*)((char*)d_ws + OFF_H2);
        pack_weights<<<98, 256, 0, stream>>>(w2, wx1, wx2, wpw, wpack);
        xprep<<<NPTS / MPREP, 512, 0, stream>>>(
            rep_pt, pts, w1, b1, b2, wc1, bc1, bx1, bx2, wpack, gH2, gX2);
        xmain<<<NPTS / 16, NTHR, 0, stream>>>(
            fts, wdw, bdw, bpw, bn_gamma, bn_beta, bn_mean, bn_var,
            wpack, gH2, gX2, out);
    } else if (d_ws != nullptr && ws_size >= (size_t)WS_PACK) {
        pack_weights<<<98, 256, 0, stream>>>(w2, wx1, wx2, wpw, wpack);
        xconv_fused<true><<<NPTS / 16, NTHR, 0, stream>>>(
            rep_pt, pts, fts, w1, b1, w2, b2, wc1, bc1, wx1, bx1, wx2, bx2,
            wdw, bdw, wpw, bpw, bn_gamma, bn_beta, bn_mean, bn_var, wpack, out);
    } else {
        xconv_fused<false><<<NPTS / 16, NTHR, 0, stream>>>(
            rep_pt, pts, fts, w1, b1, w2, b2, wc1, bc1, wx1, bx1, wx2, bx2,
            wdw, bdw, wpw, bpw, bn_gamma, bn_beta, bn_mean, bn_var,
            (const unsigned short*)nullptr, out);
    }
}

// Round 5
// 219.013 us; speedup vs baseline: 1.0732x; 1.0732x over previous
//
#include <hip/hip_runtime.h>

#define NPTS 16384
#define MPB  16
#define NTHR 512
#define WS_NEEDED 401408u

typedef __attribute__((ext_vector_type(8))) short bf16x8;
typedef __attribute__((ext_vector_type(4))) float f32x4;

__device__ __forceinline__ unsigned short f2bf(float x) {
    unsigned u = __float_as_uint(x);
    return (unsigned short)((u + 0x7FFFu + ((u >> 16) & 1u)) >> 16);
}
__device__ __forceinline__ unsigned pk2(float a, float b) {
    return (unsigned)f2bf(a) | ((unsigned)f2bf(b) << 16);
}
__device__ __forceinline__ float bf2f(unsigned short h) {
    return __uint_as_float(((unsigned)h) << 16);
}
__device__ __forceinline__ float elu_f(float x) {
    return x > 0.f ? x : (__expf(x) - 1.f);
}

// Gather one 16x16x32 B-fragment directly from a row-major fp32 matrix W[K][N].
__device__ __forceinline__ bf16x8 load_bfrag(const float* __restrict__ W, int N,
                                             int kt, int nt, int lane) {
    int k0  = kt * 32 + ((lane >> 4) << 3);
    int col = nt * 16 + (lane & 15);
    const float* s = W + k0 * N + col;
    bf16x8 r;
#pragma unroll
    for (int j = 0; j < 8; j++) r[j] = (short)f2bf(s[j * N]);
    return r;
}

// ---------------- prep: pack w2 / wx1 / wx2 / wpw into bf16 B-fragments ----
// frag order: w2 [kt*4+nt] (8), wx1 [kt*16+nt] (128), wx2 (128), wpw [kt*8+nt] (128)
__global__ void pack_weights(const float* __restrict__ w2,
                             const float* __restrict__ wx1,
                             const float* __restrict__ wx2,
                             const float* __restrict__ wpw,
                             unsigned short* __restrict__ dst) {
    int gid  = blockIdx.x * 256 + threadIdx.x;   // 98*256 = 25088 = 392*64
    int frag = gid >> 6, lane = gid & 63;
    const float* src; int N, fl;
    if      (frag <   8) { src = w2;  N =  64; fl = frag;       }
    else if (frag < 136) { src = wx1; N = 256; fl = frag - 8;   }
    else if (frag < 264) { src = wx2; N = 256; fl = frag - 136; }
    else                 { src = wpw; N = 128; fl = frag - 264; }
    int NT  = N >> 4;
    int kt  = fl / NT, nt = fl - kt * NT;
    int k0  = kt * 32 + (lane >> 4) * 8;
    int col = nt * 16 + (lane & 15);
    const float* s = src + k0 * N + col;
    unsigned v[4];
#pragma unroll
    for (int u = 0; u < 4; u++) {
        unsigned lo = f2bf(s[(2 * u) * N]);
        unsigned hi = f2bf(s[(2 * u + 1) * N]);
        v[u] = lo | (hi << 16);
    }
    *(uint4*)&dst[gid * 8] = make_uint4(v[0], v[1], v[2], v[3]);
}

// ---------------- main fused kernel -----------------------------------------
// MPB=16, 512 threads (8 waves), LDS 60928 B -> 2 blocks/CU (16 waves/CU).
// 5 barriers (was 9): A | {h2-direct on waves4-7  ||  X0 on waves0-3} | D | E | F | G
// h1 never touches LDS: each lane of the h2 MFMA computes its own A-fragment
// channels (16 of them) from 3 ptsl values + a preloaded w1 slice.
// LDS map:
//   0     s_ptsl [16][48] f32                 3072
//   3072  s_h2f  [16 m][4 nt][32 lane][8] u16 32768  (B-frag layout, slot1..F)
//   35840 overlay region 25088:
//         s_x0  [16][264] u16  8448   (slot1->D) @35840
//         s_x2f [16][32][8] u16 8192  (E->F)     @35840
//         s_x1  [16][264] u16  8448   (D->E)     @44288
//         s_dw  [16][520] u16 16640   (F->G)     @44288
template <bool PACKED>
__global__ __launch_bounds__(NTHR, 4)
void xconv_main(const float* __restrict__ rep_pt, const float* __restrict__ pts,
                const float* __restrict__ fts,
                const float* __restrict__ w1,  const float* __restrict__ b1,
                const float* __restrict__ w2,  const float* __restrict__ b2,
                const float* __restrict__ wc1, const float* __restrict__ bc1,
                const float* __restrict__ wx1, const float* __restrict__ bx1,
                const float* __restrict__ wx2, const float* __restrict__ bx2,
                const float* __restrict__ wdw, const float* __restrict__ bdw,
                const float* __restrict__ wpw, const float* __restrict__ bpw,
                const float* __restrict__ bn_gamma, const float* __restrict__ bn_beta,
                const float* __restrict__ bn_mean,  const float* __restrict__ bn_var,
                const unsigned short* __restrict__ wpack,
                float* __restrict__ out) {
    __shared__ __align__(16) char smem[60928];
    float*          s_ptsl = (float*)smem;                          // [16][48]
    unsigned short* s_h2f  = (unsigned short*)(smem + 3072);        // [16][4][32][8]
    unsigned short* s_x0   = (unsigned short*)(smem + 35840);       // [16][264]
    unsigned short* s_x2f  = (unsigned short*)(smem + 35840);       // [16][32][8]
    unsigned short* s_x1   = (unsigned short*)(smem + 44288);       // [16][264]
    unsigned short* s_dw   = (unsigned short*)(smem + 44288);       // [16][520]

    const int t    = threadIdx.x;
    const int lane = t & 63;
    const int w    = t >> 6;          // 0..7
    const int cl   = lane & 15;
    const int hh   = lane >> 4;
    const int gp0  = blockIdx.x * MPB;

    // ---- Phase A: pts_local -> LDS ----
    for (int idx = t; idx < MPB * 48; idx += NTHR) {
        int m = idx / 48, r = idx - m * 48;
        int k = r / 3,    d = r - k * 3;
        int gp = gp0 + m;
        s_ptsl[idx] = pts[(gp * 16 + k) * 3 + d] - rep_pt[gp * 3 + d];
    }
    __syncthreads();

    // ---- SLOT1: waves 4-7: h1-in-register + h2 MFMA -> s_h2f
    //             waves 0-3: X0 = elu(ptsl einsum wc1 + bc1) -> s_x0
    if (w >= 4) {
        const bf16x8* wp = (const bf16x8*)wpack;   // w2 frags at base 0
        bf16x8 Bf[8];
#pragma unroll
        for (int f = 0; f < 8; f++) {
            if (PACKED) Bf[f] = wp[f * 64 + lane];
            else        Bf[f] = load_bfrag(w2, 64, f >> 2, f & 3, lane);
        }
        float bias[4];
#pragma unroll
        for (int nt = 0; nt < 4; nt++) bias[nt] = b2[nt * 16 + cl];
        // w1 slice this lane needs: channels kt*32 + hh*8 + j
        float w1s[2][3][8], b1s[2][8];
#pragma unroll
        for (int kt = 0; kt < 2; kt++) {
#pragma unroll
            for (int d = 0; d < 3; d++)
#pragma unroll
                for (int j = 0; j < 8; j++)
                    w1s[kt][d][j] = w1[d * 64 + kt * 32 + hh * 8 + j];
#pragma unroll
            for (int j = 0; j < 8; j++) b1s[kt][j] = b1[kt * 32 + hh * 8 + j];
        }
#pragma unroll
        for (int i = 0; i < 4; i++) {
            int tile = (w - 4) * 4 + i;       // point index 0..15
            float p0 = s_ptsl[tile * 48 + cl * 3 + 0];
            float p1 = s_ptsl[tile * 48 + cl * 3 + 1];
            float p2 = s_ptsl[tile * 48 + cl * 3 + 2];
            bf16x8 a[2];
#pragma unroll
            for (int kt = 0; kt < 2; kt++) {
                unsigned v[4];
#pragma unroll
                for (int u = 0; u < 4; u++) {
                    int j0 = 2 * u, j1 = 2 * u + 1;
                    float ha = elu_f(fmaf(p0, w1s[kt][0][j0],
                                     fmaf(p1, w1s[kt][1][j0],
                                     fmaf(p2, w1s[kt][2][j0], b1s[kt][j0]))));
                    float hb = elu_f(fmaf(p0, w1s[kt][0][j1],
                                     fmaf(p1, w1s[kt][1][j1],
                                     fmaf(p2, w1s[kt][2][j1], b1s[kt][j1]))));
                    v[u] = pk2(ha, hb);
                }
                union { bf16x8 b8; uint4 u4; } ua;
                ua.u4 = make_uint4(v[0], v[1], v[2], v[3]);
                a[kt] = ua.b8;
            }
#pragma unroll
            for (int nt = 0; nt < 4; nt++) {
                f32x4 acc = {bias[nt], bias[nt], bias[nt], bias[nt]};
                acc = __builtin_amdgcn_mfma_f32_16x16x32_bf16(a[0], Bf[0 * 4 + nt], acc, 0, 0, 0);
                acc = __builtin_amdgcn_mfma_f32_16x16x32_bf16(a[1], Bf[1 * 4 + nt], acc, 0, 0, 0);
                // scatter to B-frag layout: k = 4*hh + r, lane' = (k>>3)*16+cl, j = k&7
                unsigned lo = pk2(elu_f(acc[0]), elu_f(acc[1]));
                unsigned hi = pk2(elu_f(acc[2]), elu_f(acc[3]));
                unsigned short* dp = &s_h2f[(((tile * 4 + nt) * 32) + (hh >> 1) * 16 + cl) * 8 + (hh & 1) * 4];
                *(uint2*)dp = make_uint2(lo, hi);
            }
        }
    } else {
        // X0: one output channel per thread (t = 0..255), all 16 points
        float wreg[48];                       // wc1[o][d][k] -> wreg[d*16+k]
#pragma unroll
        for (int q = 0; q < 12; q++) {
            float4 wv = *(const float4*)&wc1[t * 48 + q * 4];
            wreg[q * 4 + 0] = wv.x; wreg[q * 4 + 1] = wv.y;
            wreg[q * 4 + 2] = wv.z; wreg[q * 4 + 3] = wv.w;
        }
        float bo = bc1[t];
#pragma unroll 1
        for (int m = 0; m < MPB; m++) {
            float acc = bo;
#pragma unroll
            for (int q = 0; q < 12; q++) {
                float4 pv = *(const float4*)&s_ptsl[m * 48 + q * 4];   // flat f = k*3+d
                acc = fmaf(pv.x, wreg[((q * 4 + 0) % 3) * 16 + (q * 4 + 0) / 3], acc);
                acc = fmaf(pv.y, wreg[((q * 4 + 1) % 3) * 16 + (q * 4 + 1) / 3], acc);
                acc = fmaf(pv.z, wreg[((q * 4 + 2) % 3) * 16 + (q * 4 + 2) / 3], acc);
                acc = fmaf(pv.w, wreg[((q * 4 + 3) % 3) * 16 + (q * 4 + 3) / 3], acc);
            }
            s_x0[m * 264 + t] = f2bf(elu_f(acc));
        }
    }
    __syncthreads();

    // ---- Phase D: X1 = elu(X0 @ wx1 + bx1), MFMA, M=16,N=256,K=256; 2 nt/wave ----
    {
        const bf16x8* wp = (const bf16x8*)wpack + 512;  // wx1
        f32x4 acc[2];
#pragma unroll
        for (int q = 0; q < 2; q++) {
            float bv = bx1[(w * 2 + q) * 16 + cl];
            acc[q] = (f32x4){bv, bv, bv, bv};
        }
#pragma unroll
        for (int kt = 0; kt < 8; kt++) {
            bf16x8 a = *(const bf16x8*)&s_x0[cl * 264 + kt * 32 + hh * 8];
#pragma unroll
            for (int q = 0; q < 2; q++) {
                int nt = w * 2 + q;
                bf16x8 b;
                if (PACKED) b = wp[(kt * 16 + nt) * 64 + lane];
                else        b = load_bfrag(wx1, 256, kt, nt, lane);
                acc[q] = __builtin_amdgcn_mfma_f32_16x16x32_bf16(a, b, acc[q], 0, 0, 0);
            }
        }
#pragma unroll
        for (int q = 0; q < 2; q++) {
            int nt = w * 2 + q;
#pragma unroll
            for (int r = 0; r < 4; r++) {
                int m = hh * 4 + r;
                s_x1[m * 264 + nt * 16 + cl] = f2bf(elu_f(acc[q][r]));
            }
        }
    }
    __syncthreads();

    // ---- Phase E: X2 = X1 @ wx2 + bx2 (no act), MFMA; scatter to A-frag layout ----
    {
        const bf16x8* wp = (const bf16x8*)wpack + 8704;  // wx2
        f32x4 acc[2];
#pragma unroll
        for (int q = 0; q < 2; q++) {
            float bv = bx2[(w * 2 + q) * 16 + cl];
            acc[q] = (f32x4){bv, bv, bv, bv};
        }
#pragma unroll
        for (int kt = 0; kt < 8; kt++) {
            bf16x8 a = *(const bf16x8*)&s_x1[cl * 264 + kt * 32 + hh * 8];
#pragma unroll
            for (int q = 0; q < 2; q++) {
                int nt = w * 2 + q;
                bf16x8 b;
                if (PACKED) b = wp[(kt * 16 + nt) * 64 + lane];
                else        b = load_bfrag(wx2, 256, kt, nt, lane);
                acc[q] = __builtin_amdgcn_mfma_f32_16x16x32_bf16(a, b, acc[q], 0, 0, 0);
            }
        }
        // X2[m'][i=ntE][j=cl]; dest lane' = (j>>3)*16 + i, jj = j&7
#pragma unroll
        for (int q = 0; q < 2; q++) {
            int ntE = w * 2 + q;
            int lp  = (cl >> 3) * 16 + ntE;
            int jj  = cl & 7;
#pragma unroll
            for (int r = 0; r < 4; r++) {
                int m = hh * 4 + r;
                s_x2f[(m * 32 + lp) * 8 + jj] = f2bf(acc[q][r]);
            }
        }
    }
    __syncthreads();

    // ---- Phase F: fts_X via MFMA (zero-padded K=16) + depthwise via butterfly ----
    // waves 0..3: h2 half (channels 0..63, B-frags from LDS)
    // waves 4..7: fts half (channels 64..127, B-frags packed from global, pipelined)
    {
        const int  cH    = (w & 3) * 16 + cl;     // 0..63 within half
        const bool isF   = (w >= 4);
        const int  cFull = isF ? (64 + cH) : cH;
        float wd[16];
#pragma unroll
        for (int d = 0; d < 4; d++) {
            float4 v = *(const float4*)&wdw[cFull * 64 + d * 16 + 4 * hh];
            wd[d * 4 + 0] = v.x; wd[d * 4 + 1] = v.y;
            wd[d * 4 + 2] = v.z; wd[d * 4 + 3] = v.w;
        }
        float4 bd = *(const float4*)&bdw[cFull * 4];
        const float* ftsp = fts + (size_t)gp0 * 1024 + cH;

        float f0[8], f1[8];
        auto LDF = [&](int m, float* f) {
            if (isF && lane < 32) {
                const float* p = ftsp + (m * 16 + hh * 8) * 64;
#pragma unroll
                for (int j = 0; j < 8; j++) f[j] = p[j * 64];
            }
        };
        auto BODY = [&](int m, float* fc_, float* fn_) {
            if (m < 15) LDF(m + 1, fn_);
            bf16x8 a = {};
            if (lane < 32) a = *(const bf16x8*)&s_x2f[(m * 32 + lane) * 8];
            bf16x8 b = {};
            if (isF) {
                if (lane < 32) {
                    union { bf16x8 v; uint4 u; } ub;
                    ub.u = make_uint4(pk2(fc_[0], fc_[1]), pk2(fc_[2], fc_[3]),
                                      pk2(fc_[4], fc_[5]), pk2(fc_[6], fc_[7]));
                    b = ub.v;
                }
            } else {
                if (lane < 32) b = *(const bf16x8*)&s_h2f[((m * 4 + (w & 3)) * 32 + lane) * 8];
            }
            f32x4 acc = {0.f, 0.f, 0.f, 0.f};
            acc = __builtin_amdgcn_mfma_f32_16x16x32_bf16(a, b, acc, 0, 0, 0);
            // depthwise: rows i = 4*hh + r live in this lane; reduce across hh groups
            float o[4];
#pragma unroll
            for (int d = 0; d < 4; d++) {
                float s = acc[0] * wd[d * 4 + 0];
                s = fmaf(acc[1], wd[d * 4 + 1], s);
                s = fmaf(acc[2], wd[d * 4 + 2], s);
                s = fmaf(acc[3], wd[d * 4 + 3], s);
                s += __shfl_xor(s, 16);
                s += __shfl_xor(s, 32);
                o[d] = s;
            }
            if (hh == 0) {
                ushort4 v;
                v.x = f2bf(o[0] + bd.x); v.y = f2bf(o[1] + bd.y);
                v.z = f2bf(o[2] + bd.z); v.w = f2bf(o[3] + bd.w);
                *(ushort4*)&s_dw[m * 520 + cFull * 4] = v;
            }
        };
        LDF(0, f0);
#pragma unroll
        for (int mm = 0; mm < 8; mm++) {
            BODY(2 * mm + 0, f0, f1);
            BODY(2 * mm + 1, f1, f0);
        }
    }
    __syncthreads();

    // ---- Phase G: y = BN(elu(dw @ wpw + bpw)), MFMA M=16,N=128,K=512; 1 nt/wave ----
    {
        const bf16x8* wp = (const bf16x8*)wpack + 16896;  // wpw
        float bv = bpw[w * 16 + cl];
        f32x4 acc = {bv, bv, bv, bv};
#pragma unroll
        for (int kt = 0; kt < 16; kt++) {
            bf16x8 a = *(const bf16x8*)&s_dw[cl * 520 + kt * 32 + hh * 8];
            bf16x8 b;
            if (PACKED) b = wp[(kt * 8 + w) * 64 + lane];
            else        b = load_bfrag(wpw, 128, kt, w, lane);
            acc = __builtin_amdgcn_mfma_f32_16x16x32_bf16(a, b, acc, 0, 0, 0);
        }
        int co = w * 16 + cl;
        float scale = bn_gamma[co] * rsqrtf(bn_var[co] + 1e-5f);
        float shift = bn_beta[co] - bn_mean[co] * scale;
#pragma unroll
        for (int r = 0; r < 4; r++) {
            int m = hh * 4 + r;
            out[(gp0 + m) * 128 + co] = fmaf(elu_f(acc[r]), scale, shift);
        }
    }
}

extern "C" void kernel_launch(void* const* d_in, const int* in_sizes, int n_in,
                              void* d_out, int out_size, void* d_ws, size_t ws_size,
                              hipStream_t stream) {
    const float* rep_pt   = (const float*)d_in[0];
    const float* pts      = (const float*)d_in[1];
    const float* fts      = (const float*)d_in[2];
    const float* w1       = (const float*)d_in[3];
    const float* b1       = (const float*)d_in[4];
    const float* w2       = (const float*)d_in[5];
    const float* b2       = (const float*)d_in[6];
    const float* wc1      = (const float*)d_in[7];
    const float* bc1      = (const float*)d_in[8];
    const float* wx1      = (const float*)d_in[9];
    const float* bx1      = (const float*)d_in[10];
    const float* wx2      = (const float*)d_in[11];
    const float* bx2      = (const float*)d_in[12];
    const float* wdw      = (const float*)d_in[13];
    const float* bdw      = (const float*)d_in[14];
    const float* wpw      = (const float*)d_in[15];
    const float* bpw      = (const float*)d_in[16];
    const float* bn_gamma = (const float*)d_in[17];
    const float* bn_beta  = (const float*)d_in[18];
    const float* bn_mean  = (const float*)d_in[19];
    const float* bn_var   = (const float*)d_in[20];
    float* out = (float*)d_out;

    const bool packed = (d_ws != nullptr) && (ws_size >= (size_t)WS_NEEDED);
    unsigned short* wpack = (unsigned short*)d_ws;

    if (packed) {
        pack_weights<<<98, 256, 0, stream>>>(w2, wx1, wx2, wpw, wpack);
        xconv_main<true><<<NPTS / MPB, NTHR, 0, stream>>>(
            rep_pt, pts, fts, w1, b1, w2, b2, wc1, bc1, wx1, bx1, wx2, bx2,
            wdw, bdw, wpw, bpw, bn_gamma, bn_beta, bn_mean, bn_var, wpack, out);
    } else {
        xconv_main<false><<<NPTS / MPB, NTHR, 0, stream>>>(
            rep_pt, pts, fts, w1, b1, w2, b2, wc1, bc1, wx1, bx1, wx2, bx2,
            wdw, bdw, wpw, bpw, bn_gamma, bn_beta, bn_mean, bn_var, (const unsigned short*)nullptr, out);
    }
}

// Round 6
// 192.127 us; speedup vs baseline: 1.2234x; 1.1399x over previous
//
#include <hip/hip_runtime.h>

#define NPTS 16384
#define MPB  16
#define NTHR 512
#define WS_NEEDED 401408u

typedef __attribute__((ext_vector_type(8))) short bf16x8;
typedef __attribute__((ext_vector_type(4))) float f32x4;

__device__ __forceinline__ unsigned short f2bf(float x) {
    unsigned u = __float_as_uint(x);
    return (unsigned short)((u + 0x7FFFu + ((u >> 16) & 1u)) >> 16);
}
__device__ __forceinline__ unsigned pk2(float a, float b) {
    return (unsigned)f2bf(a) | ((unsigned)f2bf(b) << 16);
}
__device__ __forceinline__ float bf2f(unsigned short h) {
    return __uint_as_float(((unsigned)h) << 16);
}
__device__ __forceinline__ float elu_f(float x) {
    return x > 0.f ? x : (__expf(x) - 1.f);
}

// Gather one 16x16x32 B-fragment directly from a row-major fp32 matrix W[K][N].
__device__ __forceinline__ bf16x8 load_bfrag(const float* __restrict__ W, int N,
                                             int kt, int nt, int lane) {
    int k0  = kt * 32 + ((lane >> 4) << 3);
    int col = nt * 16 + (lane & 15);
    const float* s = W + k0 * N + col;
    bf16x8 r;
#pragma unroll
    for (int j = 0; j < 8; j++) r[j] = (short)f2bf(s[j * N]);
    return r;
}

// ---------------- prep: pack w2 / wx1 / wx2 / wpw into bf16 B-fragments ----
// frag order: w2 [kt*4+nt] (8), wx1 [kt*16+nt] (128), wx2 (128), wpw [kt*8+nt] (128)
__global__ void pack_weights(const float* __restrict__ w2,
                             const float* __restrict__ wx1,
                             const float* __restrict__ wx2,
                             const float* __restrict__ wpw,
                             unsigned short* __restrict__ dst) {
    int gid  = blockIdx.x * 256 + threadIdx.x;   // 98*256 = 25088 = 392*64
    int frag = gid >> 6, lane = gid & 63;
    const float* src; int N, fl;
    if      (frag <   8) { src = w2;  N =  64; fl = frag;       }
    else if (frag < 136) { src = wx1; N = 256; fl = frag - 8;   }
    else if (frag < 264) { src = wx2; N = 256; fl = frag - 136; }
    else                 { src = wpw; N = 128; fl = frag - 264; }
    int NT  = N >> 4;
    int kt  = fl / NT, nt = fl - kt * NT;
    int k0  = kt * 32 + (lane >> 4) * 8;
    int col = nt * 16 + (lane & 15);
    const float* s = src + k0 * N + col;
    unsigned v[4];
#pragma unroll
    for (int u = 0; u < 4; u++) {
        unsigned lo = f2bf(s[(2 * u) * N]);
        unsigned hi = f2bf(s[(2 * u + 1) * N]);
        v[u] = lo | (hi << 16);
    }
    *(uint4*)&dst[gid * 8] = make_uint4(v[0], v[1], v[2], v[3]);
}

// ---------------- main fused kernel -----------------------------------------
// MPB=16, 512 threads (8 waves), LDS 60928 B.
// 5 barriers: A | {h2-direct on waves4-7 || X0 on waves0-3} | D | E | F | G
// launch_bounds min-waves=2: VGPR cap ~256 (r5's min-waves=4 pinned 64 regs and
// spilled ~128 B/thread to scratch -> +106 MB HBM, +18 us. Keep headroom!).
// Slot-1 h2 loads B-frags on the fly (no Bf[8] array) to stay ~100 live regs.
// LDS map:
//   0     s_ptsl [16][48] f32                 3072
//   3072  s_h2f  [16 m][4 nt][32 lane][8] u16 32768  (B-frag layout, slot1..F)
//   35840 overlay region 25088:
//         s_x0  [16][264] u16  8448   (slot1->D) @35840
//         s_x2f [16][32][8] u16 8192  (E->F)     @35840
//         s_x1  [16][264] u16  8448   (D->E)     @44288
//         s_dw  [16][520] u16 16640   (F->G)     @44288
template <bool PACKED>
__global__ __launch_bounds__(NTHR, 2)
void xconv_main(const float* __restrict__ rep_pt, const float* __restrict__ pts,
                const float* __restrict__ fts,
                const float* __restrict__ w1,  const float* __restrict__ b1,
                const float* __restrict__ w2,  const float* __restrict__ b2,
                const float* __restrict__ wc1, const float* __restrict__ bc1,
                const float* __restrict__ wx1, const float* __restrict__ bx1,
                const float* __restrict__ wx2, const float* __restrict__ bx2,
                const float* __restrict__ wdw, const float* __restrict__ bdw,
                const float* __restrict__ wpw, const float* __restrict__ bpw,
                const float* __restrict__ bn_gamma, const float* __restrict__ bn_beta,
                const float* __restrict__ bn_mean,  const float* __restrict__ bn_var,
                const unsigned short* __restrict__ wpack,
                float* __restrict__ out) {
    __shared__ __align__(16) char smem[60928];
    float*          s_ptsl = (float*)smem;                          // [16][48]
    unsigned short* s_h2f  = (unsigned short*)(smem + 3072);        // [16][4][32][8]
    unsigned short* s_x0   = (unsigned short*)(smem + 35840);       // [16][264]
    unsigned short* s_x2f  = (unsigned short*)(smem + 35840);       // [16][32][8]
    unsigned short* s_x1   = (unsigned short*)(smem + 44288);       // [16][264]
    unsigned short* s_dw   = (unsigned short*)(smem + 44288);       // [16][520]

    const int t    = threadIdx.x;
    const int lane = t & 63;
    const int w    = t >> 6;          // 0..7
    const int cl   = lane & 15;
    const int hh   = lane >> 4;
    const int gp0  = blockIdx.x * MPB;

    // ---- Phase A: pts_local -> LDS ----
    for (int idx = t; idx < MPB * 48; idx += NTHR) {
        int m = idx / 48, r = idx - m * 48;
        int k = r / 3,    d = r - k * 3;
        int gp = gp0 + m;
        s_ptsl[idx] = pts[(gp * 16 + k) * 3 + d] - rep_pt[gp * 3 + d];
    }
    __syncthreads();

    // ---- SLOT1: waves 4-7: h1-in-register + h2 MFMA -> s_h2f
    //             waves 0-3: X0 = elu(ptsl einsum wc1 + bc1) -> s_x0
    if (w >= 4) {
        const bf16x8* wp = (const bf16x8*)wpack;   // w2 frags at base 0
        float bias[4];
#pragma unroll
        for (int nt = 0; nt < 4; nt++) bias[nt] = b2[nt * 16 + cl];
        // w1 slice this lane needs: channels kt*32 + hh*8 + j
        float w1s[2][3][8], b1s[2][8];
#pragma unroll
        for (int kt = 0; kt < 2; kt++) {
#pragma unroll
            for (int d = 0; d < 3; d++)
#pragma unroll
                for (int j = 0; j < 8; j++)
                    w1s[kt][d][j] = w1[d * 64 + kt * 32 + hh * 8 + j];
#pragma unroll
            for (int j = 0; j < 8; j++) b1s[kt][j] = b1[kt * 32 + hh * 8 + j];
        }
#pragma unroll
        for (int i = 0; i < 4; i++) {
            int tile = (w - 4) * 4 + i;       // point index 0..15
            float p0 = s_ptsl[tile * 48 + cl * 3 + 0];
            float p1 = s_ptsl[tile * 48 + cl * 3 + 1];
            float p2 = s_ptsl[tile * 48 + cl * 3 + 2];
            bf16x8 a[2];
#pragma unroll
            for (int kt = 0; kt < 2; kt++) {
                unsigned v[4];
#pragma unroll
                for (int u = 0; u < 4; u++) {
                    int j0 = 2 * u, j1 = 2 * u + 1;
                    float ha = elu_f(fmaf(p0, w1s[kt][0][j0],
                                     fmaf(p1, w1s[kt][1][j0],
                                     fmaf(p2, w1s[kt][2][j0], b1s[kt][j0]))));
                    float hb = elu_f(fmaf(p0, w1s[kt][0][j1],
                                     fmaf(p1, w1s[kt][1][j1],
                                     fmaf(p2, w1s[kt][2][j1], b1s[kt][j1]))));
                    v[u] = pk2(ha, hb);
                }
                union { bf16x8 b8; uint4 u4; } ua;
                ua.u4 = make_uint4(v[0], v[1], v[2], v[3]);
                a[kt] = ua.b8;
            }
#pragma unroll
            for (int nt = 0; nt < 4; nt++) {
                bf16x8 b0, b1f;
                if (PACKED) { b0 = wp[(0 * 4 + nt) * 64 + lane]; b1f = wp[(1 * 4 + nt) * 64 + lane]; }
                else        { b0 = load_bfrag(w2, 64, 0, nt, lane); b1f = load_bfrag(w2, 64, 1, nt, lane); }
                f32x4 acc = {bias[nt], bias[nt], bias[nt], bias[nt]};
                acc = __builtin_amdgcn_mfma_f32_16x16x32_bf16(a[0], b0,  acc, 0, 0, 0);
                acc = __builtin_amdgcn_mfma_f32_16x16x32_bf16(a[1], b1f, acc, 0, 0, 0);
                // scatter to B-frag layout: k = 4*hh + r, lane' = (k>>3)*16+cl, j = k&7
                unsigned lo = pk2(elu_f(acc[0]), elu_f(acc[1]));
                unsigned hi = pk2(elu_f(acc[2]), elu_f(acc[3]));
                unsigned short* dp = &s_h2f[(((tile * 4 + nt) * 32) + (hh >> 1) * 16 + cl) * 8 + (hh & 1) * 4];
                *(uint2*)dp = make_uint2(lo, hi);
            }
        }
    } else {
        // X0: one output channel per thread (t = 0..255), all 16 points
        float wreg[48];                       // wc1[o][d][k] -> wreg[d*16+k]
#pragma unroll
        for (int q = 0; q < 12; q++) {
            float4 wv = *(const float4*)&wc1[t * 48 + q * 4];
            wreg[q * 4 + 0] = wv.x; wreg[q * 4 + 1] = wv.y;
            wreg[q * 4 + 2] = wv.z; wreg[q * 4 + 3] = wv.w;
        }
        float bo = bc1[t];
#pragma unroll 1
        for (int m = 0; m < MPB; m++) {
            float acc = bo;
#pragma unroll
            for (int q = 0; q < 12; q++) {
                float4 pv = *(const float4*)&s_ptsl[m * 48 + q * 4];   // flat f = k*3+d
                acc = fmaf(pv.x, wreg[((q * 4 + 0) % 3) * 16 + (q * 4 + 0) / 3], acc);
                acc = fmaf(pv.y, wreg[((q * 4 + 1) % 3) * 16 + (q * 4 + 1) / 3], acc);
                acc = fmaf(pv.z, wreg[((q * 4 + 2) % 3) * 16 + (q * 4 + 2) / 3], acc);
                acc = fmaf(pv.w, wreg[((q * 4 + 3) % 3) * 16 + (q * 4 + 3) / 3], acc);
            }
            s_x0[m * 264 + t] = f2bf(elu_f(acc));
        }
    }
    __syncthreads();

    // ---- Phase D: X1 = elu(X0 @ wx1 + bx1), MFMA, M=16,N=256,K=256; 2 nt/wave ----
    {
        const bf16x8* wp = (const bf16x8*)wpack + 512;  // wx1
        f32x4 acc[2];
#pragma unroll
        for (int q = 0; q < 2; q++) {
            float bv = bx1[(w * 2 + q) * 16 + cl];
            acc[q] = (f32x4){bv, bv, bv, bv};
        }
#pragma unroll
        for (int kt = 0; kt < 8; kt++) {
            bf16x8 a = *(const bf16x8*)&s_x0[cl * 264 + kt * 32 + hh * 8];
#pragma unroll
            for (int q = 0; q < 2; q++) {
                int nt = w * 2 + q;
                bf16x8 b;
                if (PACKED) b = wp[(kt * 16 + nt) * 64 + lane];
                else        b = load_bfrag(wx1, 256, kt, nt, lane);
                acc[q] = __builtin_amdgcn_mfma_f32_16x16x32_bf16(a, b, acc[q], 0, 0, 0);
            }
        }
#pragma unroll
        for (int q = 0; q < 2; q++) {
            int nt = w * 2 + q;
#pragma unroll
            for (int r = 0; r < 4; r++) {
                int m = hh * 4 + r;
                s_x1[m * 264 + nt * 16 + cl] = f2bf(elu_f(acc[q][r]));
            }
        }
    }
    __syncthreads();

    // ---- Phase E: X2 = X1 @ wx2 + bx2 (no act), MFMA; scatter to A-frag layout ----
    {
        const bf16x8* wp = (const bf16x8*)wpack + 8704;  // wx2
        f32x4 acc[2];
#pragma unroll
        for (int q = 0; q < 2; q++) {
            float bv = bx2[(w * 2 + q) * 16 + cl];
            acc[q] = (f32x4){bv, bv, bv, bv};
        }
#pragma unroll
        for (int kt = 0; kt < 8; kt++) {
            bf16x8 a = *(const bf16x8*)&s_x1[cl * 264 + kt * 32 + hh * 8];
#pragma unroll
            for (int q = 0; q < 2; q++) {
                int nt = w * 2 + q;
                bf16x8 b;
                if (PACKED) b = wp[(kt * 16 + nt) * 64 + lane];
                else        b = load_bfrag(wx2, 256, kt, nt, lane);
                acc[q] = __builtin_amdgcn_mfma_f32_16x16x32_bf16(a, b, acc[q], 0, 0, 0);
            }
        }
        // X2[m'][i=ntE][j=cl]; dest lane' = (j>>3)*16 + i, jj = j&7
#pragma unroll
        for (int q = 0; q < 2; q++) {
            int ntE = w * 2 + q;
            int lp  = (cl >> 3) * 16 + ntE;
            int jj  = cl & 7;
#pragma unroll
            for (int r = 0; r < 4; r++) {
                int m = hh * 4 + r;
                s_x2f[(m * 32 + lp) * 8 + jj] = f2bf(acc[q][r]);
            }
        }
    }
    __syncthreads();

    // ---- Phase F: fts_X via MFMA (zero-padded K=16) + depthwise via butterfly ----
    // waves 0..3: h2 half (channels 0..63, B-frags from LDS)
    // waves 4..7: fts half (channels 64..127, B-frags packed from global, pipelined)
    {
        const int  cH    = (w & 3) * 16 + cl;     // 0..63 within half
        const bool isF   = (w >= 4);
        const int  cFull = isF ? (64 + cH) : cH;
        float wd[16];
#pragma unroll
        for (int d = 0; d < 4; d++) {
            float4 v = *(const float4*)&wdw[cFull * 64 + d * 16 + 4 * hh];
            wd[d * 4 + 0] = v.x; wd[d * 4 + 1] = v.y;
            wd[d * 4 + 2] = v.z; wd[d * 4 + 3] = v.w;
        }
        float4 bd = *(const float4*)&bdw[cFull * 4];
        const float* ftsp = fts + (size_t)gp0 * 1024 + cH;

        float f0[8], f1[8];
        auto LDF = [&](int m, float* f) {
            if (isF && lane < 32) {
                const float* p = ftsp + (m * 16 + hh * 8) * 64;
#pragma unroll
                for (int j = 0; j < 8; j++) f[j] = p[j * 64];
            }
        };
        auto BODY = [&](int m, float* fc_, float* fn_) {
            if (m < 15) LDF(m + 1, fn_);
            bf16x8 a = {};
            if (lane < 32) a = *(const bf16x8*)&s_x2f[(m * 32 + lane) * 8];
            bf16x8 b = {};
            if (isF) {
                if (lane < 32) {
                    union { bf16x8 v; uint4 u; } ub;
                    ub.u = make_uint4(pk2(fc_[0], fc_[1]), pk2(fc_[2], fc_[3]),
                                      pk2(fc_[4], fc_[5]), pk2(fc_[6], fc_[7]));
                    b = ub.v;
                }
            } else {
                if (lane < 32) b = *(const bf16x8*)&s_h2f[((m * 4 + (w & 3)) * 32 + lane) * 8];
            }
            f32x4 acc = {0.f, 0.f, 0.f, 0.f};
            acc = __builtin_amdgcn_mfma_f32_16x16x32_bf16(a, b, acc, 0, 0, 0);
            // depthwise: rows i = 4*hh + r live in this lane; reduce across hh groups
            float o[4];
#pragma unroll
            for (int d = 0; d < 4; d++) {
                float s = acc[0] * wd[d * 4 + 0];
                s = fmaf(acc[1], wd[d * 4 + 1], s);
                s = fmaf(acc[2], wd[d * 4 + 2], s);
                s = fmaf(acc[3], wd[d * 4 + 3], s);
                s += __shfl_xor(s, 16);
                s += __shfl_xor(s, 32);
                o[d] = s;
            }
            if (hh == 0) {
                ushort4 v;
                v.x = f2bf(o[0] + bd.x); v.y = f2bf(o[1] + bd.y);
                v.z = f2bf(o[2] + bd.z); v.w = f2bf(o[3] + bd.w);
                *(ushort4*)&s_dw[m * 520 + cFull * 4] = v;
            }
        };
        LDF(0, f0);
#pragma unroll
        for (int mm = 0; mm < 8; mm++) {
            BODY(2 * mm + 0, f0, f1);
            BODY(2 * mm + 1, f1, f0);
        }
    }
    __syncthreads();

    // ---- Phase G: y = BN(elu(dw @ wpw + bpw)), MFMA M=16,N=128,K=512; 1 nt/wave ----
    {
        const bf16x8* wp = (const bf16x8*)wpack + 16896;  // wpw
        float bv = bpw[w * 16 + cl];
        f32x4 acc = {bv, bv, bv, bv};
#pragma unroll
        for (int kt = 0; kt < 16; kt++) {
            bf16x8 a = *(const bf16x8*)&s_dw[cl * 520 + kt * 32 + hh * 8];
            bf16x8 b;
            if (PACKED) b = wp[(kt * 8 + w) * 64 + lane];
            else        b = load_bfrag(wpw, 128, kt, w, lane);
            acc = __builtin_amdgcn_mfma_f32_16x16x32_bf16(a, b, acc, 0, 0, 0);
        }
        int co = w * 16 + cl;
        float scale = bn_gamma[co] * rsqrtf(bn_var[co] + 1e-5f);
        float shift = bn_beta[co] - bn_mean[co] * scale;
#pragma unroll
        for (int r = 0; r < 4; r++) {
            int m = hh * 4 + r;
            out[(gp0 + m) * 128 + co] = fmaf(elu_f(acc[r]), scale, shift);
        }
    }
}

extern "C" void kernel_launch(void* const* d_in, const int* in_sizes, int n_in,
                              void* d_out, int out_size, void* d_ws, size_t ws_size,
                              hipStream_t stream) {
    const float* rep_pt   = (const float*)d_in[0];
    const float* pts      = (const float*)d_in[1];
    const float* fts      = (const float*)d_in[2];
    const float* w1       = (const float*)d_in[3];
    const float* b1       = (const float*)d_in[4];
    const float* w2       = (const float*)d_in[5];
    const float* b2       = (const float*)d_in[6];
    const float* wc1      = (const float*)d_in[7];
    const float* bc1      = (const float*)d_in[8];
    const float* wx1      = (const float*)d_in[9];
    const float* bx1      = (const float*)d_in[10];
    const float* wx2      = (const float*)d_in[11];
    const float* bx2      = (const float*)d_in[12];
    const float* wdw      = (const float*)d_in[13];
    const float* bdw      = (const float*)d_in[14];
    const float* wpw      = (const float*)d_in[15];
    const float* bpw      = (const float*)d_in[16];
    const float* bn_gamma = (const float*)d_in[17];
    const float* bn_beta  = (const float*)d_in[18];
    const float* bn_mean  = (const float*)d_in[19];
    const float* bn_var   = (const float*)d_in[20];
    float* out = (float*)d_out;

    const bool packed = (d_ws != nullptr) && (ws_size >= (size_t)WS_NEEDED);
    unsigned short* wpack = (unsigned short*)d_ws;

    if (packed) {
        pack_weights<<<98, 256, 0, stream>>>(w2, wx1, wx2, wpw, wpack);
        xconv_main<true><<<NPTS / MPB, NTHR, 0, stream>>>(
            rep_pt, pts, fts, w1, b1, w2, b2, wc1, bc1, wx1, bx1, wx2, bx2,
            wdw, bdw, wpw, bpw, bn_gamma, bn_beta, bn_mean, bn_var, wpack, out);
    } else {
        xconv_main<false><<<NPTS / MPB, NTHR, 0, stream>>>(
            rep_pt, pts, fts, w1, b1, w2, b2, wc1, bc1, wx1, bx1, wx2, bx2,
            wdw, bdw, wpw, bpw, bn_gamma, bn_beta, bn_mean, bn_var, (const unsigned short*)nullptr, out);
    }
}

// Round 7
// 185.761 us; speedup vs baseline: 1.2653x; 1.0343x over previous
//
#include <hip/hip_runtime.h>

#define NPTS 16384
#define MPB  16
#define NTHR 512
#define WS_NEEDED 401408u

typedef __attribute__((ext_vector_type(8))) short bf16x8;
typedef __attribute__((ext_vector_type(4))) float f32x4;

__device__ __forceinline__ unsigned short f2bf(float x) {
    unsigned u = __float_as_uint(x);
    return (unsigned short)((u + 0x7FFFu + ((u >> 16) & 1u)) >> 16);
}
__device__ __forceinline__ unsigned pk2(float a, float b) {
    return (unsigned)f2bf(a) | ((unsigned)f2bf(b) << 16);
}
__device__ __forceinline__ float bf2f(unsigned short h) {
    return __uint_as_float(((unsigned)h) << 16);
}
__device__ __forceinline__ float elu_f(float x) {
    return x > 0.f ? x : (__expf(x) - 1.f);
}

// Gather one 16x16x32 B-fragment directly from a row-major fp32 matrix W[K][N].
__device__ __forceinline__ bf16x8 load_bfrag(const float* __restrict__ W, int N,
                                             int kt, int nt, int lane) {
    int k0  = kt * 32 + ((lane >> 4) << 3);
    int col = nt * 16 + (lane & 15);
    const float* s = W + k0 * N + col;
    bf16x8 r;
#pragma unroll
    for (int j = 0; j < 8; j++) r[j] = (short)f2bf(s[j * N]);
    return r;
}

// ---------------- prep: pack w2 / wx1 / wx2 / wpw into bf16 B-fragments ----
// frag order: w2 [kt*4+nt] (8), wx1 [kt*16+nt] (128), wx2 (128), wpw [kt*8+nt] (128)
__global__ void pack_weights(const float* __restrict__ w2,
                             const float* __restrict__ wx1,
                             const float* __restrict__ wx2,
                             const float* __restrict__ wpw,
                             unsigned short* __restrict__ dst) {
    int gid  = blockIdx.x * 256 + threadIdx.x;   // 98*256 = 25088 = 392*64
    int frag = gid >> 6, lane = gid & 63;
    const float* src; int N, fl;
    if      (frag <   8) { src = w2;  N =  64; fl = frag;       }
    else if (frag < 136) { src = wx1; N = 256; fl = frag - 8;   }
    else if (frag < 264) { src = wx2; N = 256; fl = frag - 136; }
    else                 { src = wpw; N = 128; fl = frag - 264; }
    int NT  = N >> 4;
    int kt  = fl / NT, nt = fl - kt * NT;
    int k0  = kt * 32 + (lane >> 4) * 8;
    int col = nt * 16 + (lane & 15);
    const float* s = src + k0 * N + col;
    unsigned v[4];
#pragma unroll
    for (int u = 0; u < 4; u++) {
        unsigned lo = f2bf(s[(2 * u) * N]);
        unsigned hi = f2bf(s[(2 * u + 1) * N]);
        v[u] = lo | (hi << 16);
    }
    *(uint4*)&dst[gid * 8] = make_uint4(v[0], v[1], v[2], v[3]);
}

// ---------------- main fused kernel -----------------------------------------
// MPB=16, 512 threads (8 waves), LDS 60928 B -> 2 blocks/CU.
// 5 barriers: A | {h2 on waves4-7 || X0 on waves0-3} | D | E | F | G
// Round-7 change: explicit load batching (A[8]/B[8] register arrays) in D/E/G,
// hoisted w2 frag loads in slot1, depth-3 fts prefetch in F. Targets the
// latency serialization visible at VGPR=64 (only ~4 loads in flight).
// Keep VGPR <= 128 so LDS (2 blocks/CU = 4 waves/SIMD) stays the occupancy cap.
// LDS map:
//   0     s_ptsl [16][48] f32                 3072
//   3072  s_h2f  [16 m][4 nt][32 lane][8] u16 32768  (B-frag layout, slot1..F)
//   35840 overlay region 25088:
//         s_x0  [16][264] u16  8448   (slot1->D) @35840
//         s_x2f [16][32][8] u16 8192  (E->F)     @35840
//         s_x1  [16][264] u16  8448   (D->E)     @44288
//         s_dw  [16][520] u16 16640   (F->G)     @44288
template <bool PACKED>
__global__ __launch_bounds__(NTHR, 2)
void xconv_main(const float* __restrict__ rep_pt, const float* __restrict__ pts,
                const float* __restrict__ fts,
                const float* __restrict__ w1,  const float* __restrict__ b1,
                const float* __restrict__ w2,  const float* __restrict__ b2,
                const float* __restrict__ wc1, const float* __restrict__ bc1,
                const float* __restrict__ wx1, const float* __restrict__ bx1,
                const float* __restrict__ wx2, const float* __restrict__ bx2,
                const float* __restrict__ wdw, const float* __restrict__ bdw,
                const float* __restrict__ wpw, const float* __restrict__ bpw,
                const float* __restrict__ bn_gamma, const float* __restrict__ bn_beta,
                const float* __restrict__ bn_mean,  const float* __restrict__ bn_var,
                const unsigned short* __restrict__ wpack,
                float* __restrict__ out) {
    __shared__ __align__(16) char smem[60928];
    float*          s_ptsl = (float*)smem;                          // [16][48]
    unsigned short* s_h2f  = (unsigned short*)(smem + 3072);        // [16][4][32][8]
    unsigned short* s_x0   = (unsigned short*)(smem + 35840);       // [16][264]
    unsigned short* s_x2f  = (unsigned short*)(smem + 35840);       // [16][32][8]
    unsigned short* s_x1   = (unsigned short*)(smem + 44288);       // [16][264]
    unsigned short* s_dw   = (unsigned short*)(smem + 44288);       // [16][520]

    const int t    = threadIdx.x;
    const int lane = t & 63;
    const int w    = t >> 6;          // 0..7
    const int cl   = lane & 15;
    const int hh   = lane >> 4;
    const int gp0  = blockIdx.x * MPB;

    // ---- Phase A: pts_local -> LDS ----
    for (int idx = t; idx < MPB * 48; idx += NTHR) {
        int m = idx / 48, r = idx - m * 48;
        int k = r / 3,    d = r - k * 3;
        int gp = gp0 + m;
        s_ptsl[idx] = pts[(gp * 16 + k) * 3 + d] - rep_pt[gp * 3 + d];
    }
    __syncthreads();

    // ---- SLOT1: waves 4-7: h1-in-register + h2 MFMA -> s_h2f
    //             waves 0-3: X0 = elu(ptsl einsum wc1 + bc1) -> s_x0
    if (w >= 4) {
        const bf16x8* wp = (const bf16x8*)wpack;   // w2 frags at base 0
        // w1 slice this lane needs: channels kt*32 + hh*8 + j  (dead after af)
        float w1s[2][3][8], b1s[2][8];
#pragma unroll
        for (int kt = 0; kt < 2; kt++) {
#pragma unroll
            for (int d = 0; d < 3; d++)
#pragma unroll
                for (int j = 0; j < 8; j++)
                    w1s[kt][d][j] = w1[d * 64 + kt * 32 + hh * 8 + j];
#pragma unroll
            for (int j = 0; j < 8; j++) b1s[kt][j] = b1[kt * 32 + hh * 8 + j];
        }
        // compute A-frags for this wave's 4 tiles up front
        bf16x8 af[4][2];
#pragma unroll
        for (int i = 0; i < 4; i++) {
            int tile = (w - 4) * 4 + i;       // point index 0..15
            float p0 = s_ptsl[tile * 48 + cl * 3 + 0];
            float p1 = s_ptsl[tile * 48 + cl * 3 + 1];
            float p2 = s_ptsl[tile * 48 + cl * 3 + 2];
#pragma unroll
            for (int kt = 0; kt < 2; kt++) {
                unsigned v[4];
#pragma unroll
                for (int u = 0; u < 4; u++) {
                    int j0 = 2 * u, j1 = 2 * u + 1;
                    float ha = elu_f(fmaf(p0, w1s[kt][0][j0],
                                     fmaf(p1, w1s[kt][1][j0],
                                     fmaf(p2, w1s[kt][2][j0], b1s[kt][j0]))));
                    float hb = elu_f(fmaf(p0, w1s[kt][0][j1],
                                     fmaf(p1, w1s[kt][1][j1],
                                     fmaf(p2, w1s[kt][2][j1], b1s[kt][j1]))));
                    v[u] = pk2(ha, hb);
                }
                union { bf16x8 b8; uint4 u4; } ua;
                ua.u4 = make_uint4(v[0], v[1], v[2], v[3]);
                af[i][kt] = ua.b8;
            }
        }
        float bias[4];
#pragma unroll
        for (int nt = 0; nt < 4; nt++) bias[nt] = b2[nt * 16 + cl];
        // nt loop with hoisted B-frag loads (each frag loaded once, reused x4)
#pragma unroll
        for (int nt = 0; nt < 4; nt++) {
            bf16x8 b0, b1f;
            if (PACKED) { b0 = wp[(0 * 4 + nt) * 64 + lane]; b1f = wp[(1 * 4 + nt) * 64 + lane]; }
            else        { b0 = load_bfrag(w2, 64, 0, nt, lane); b1f = load_bfrag(w2, 64, 1, nt, lane); }
#pragma unroll
            for (int i = 0; i < 4; i++) {
                int tile = (w - 4) * 4 + i;
                f32x4 acc = {bias[nt], bias[nt], bias[nt], bias[nt]};
                acc = __builtin_amdgcn_mfma_f32_16x16x32_bf16(af[i][0], b0,  acc, 0, 0, 0);
                acc = __builtin_amdgcn_mfma_f32_16x16x32_bf16(af[i][1], b1f, acc, 0, 0, 0);
                // scatter to B-frag layout: k = 4*hh + r, lane' = (k>>3)*16+cl, j = k&7
                unsigned lo = pk2(elu_f(acc[0]), elu_f(acc[1]));
                unsigned hi = pk2(elu_f(acc[2]), elu_f(acc[3]));
                unsigned short* dp = &s_h2f[(((tile * 4 + nt) * 32) + (hh >> 1) * 16 + cl) * 8 + (hh & 1) * 4];
                *(uint2*)dp = make_uint2(lo, hi);
            }
        }
    } else {
        // X0: one output channel per thread (t = 0..255), all 16 points
        float wreg[48];                       // wc1[o][d][k] -> wreg[d*16+k]
#pragma unroll
        for (int q = 0; q < 12; q++) {
            float4 wv = *(const float4*)&wc1[t * 48 + q * 4];
            wreg[q * 4 + 0] = wv.x; wreg[q * 4 + 1] = wv.y;
            wreg[q * 4 + 2] = wv.z; wreg[q * 4 + 3] = wv.w;
        }
        float bo = bc1[t];
#pragma unroll 1
        for (int m = 0; m < MPB; m++) {
            float acc = bo;
#pragma unroll
            for (int q = 0; q < 12; q++) {
                float4 pv = *(const float4*)&s_ptsl[m * 48 + q * 4];   // flat f = k*3+d
                acc = fmaf(pv.x, wreg[((q * 4 + 0) % 3) * 16 + (q * 4 + 0) / 3], acc);
                acc = fmaf(pv.y, wreg[((q * 4 + 1) % 3) * 16 + (q * 4 + 1) / 3], acc);
                acc = fmaf(pv.z, wreg[((q * 4 + 2) % 3) * 16 + (q * 4 + 2) / 3], acc);
                acc = fmaf(pv.w, wreg[((q * 4 + 3) % 3) * 16 + (q * 4 + 3) / 3], acc);
            }
            s_x0[m * 264 + t] = f2bf(elu_f(acc));
        }
    }
    __syncthreads();

    // ---- Phase D: X1 = elu(X0 @ wx1 + bx1), MFMA M=16,N=256,K=256; 2 nt/wave ----
    // Batched: A[8] LDS reads up front, B-frags in register batches of 8.
    {
        const bf16x8* wp = (const bf16x8*)wpack + 512;  // wx1
        bf16x8 A[8];
#pragma unroll
        for (int kt = 0; kt < 8; kt++)
            A[kt] = *(const bf16x8*)&s_x0[cl * 264 + kt * 32 + hh * 8];
        f32x4 acc[2];
#pragma unroll
        for (int q = 0; q < 2; q++) {
            float bv = bx1[(w * 2 + q) * 16 + cl];
            acc[q] = (f32x4){bv, bv, bv, bv};
        }
#pragma unroll
        for (int kb = 0; kb < 2; kb++) {
            bf16x8 B0[4], B1[4];
#pragma unroll
            for (int j = 0; j < 4; j++) {
                int kt = kb * 4 + j;
                if (PACKED) { B0[j] = wp[(kt * 16 + w * 2 + 0) * 64 + lane];
                              B1[j] = wp[(kt * 16 + w * 2 + 1) * 64 + lane]; }
                else        { B0[j] = load_bfrag(wx1, 256, kt, w * 2 + 0, lane);
                              B1[j] = load_bfrag(wx1, 256, kt, w * 2 + 1, lane); }
            }
#pragma unroll
            for (int j = 0; j < 4; j++) {
                acc[0] = __builtin_amdgcn_mfma_f32_16x16x32_bf16(A[kb * 4 + j], B0[j], acc[0], 0, 0, 0);
                acc[1] = __builtin_amdgcn_mfma_f32_16x16x32_bf16(A[kb * 4 + j], B1[j], acc[1], 0, 0, 0);
            }
        }
#pragma unroll
        for (int q = 0; q < 2; q++) {
            int nt = w * 2 + q;
#pragma unroll
            for (int r = 0; r < 4; r++) {
                int m = hh * 4 + r;
                s_x1[m * 264 + nt * 16 + cl] = f2bf(elu_f(acc[q][r]));
            }
        }
    }
    __syncthreads();

    // ---- Phase E: X2 = X1 @ wx2 + bx2 (no act), MFMA; scatter to A-frag layout ----
    {
        const bf16x8* wp = (const bf16x8*)wpack + 8704;  // wx2
        bf16x8 A[8];
#pragma unroll
        for (int kt = 0; kt < 8; kt++)
            A[kt] = *(const bf16x8*)&s_x1[cl * 264 + kt * 32 + hh * 8];
        f32x4 acc[2];
#pragma unroll
        for (int q = 0; q < 2; q++) {
            float bv = bx2[(w * 2 + q) * 16 + cl];
            acc[q] = (f32x4){bv, bv, bv, bv};
        }
#pragma unroll
        for (int kb = 0; kb < 2; kb++) {
            bf16x8 B0[4], B1[4];
#pragma unroll
            for (int j = 0; j < 4; j++) {
                int kt = kb * 4 + j;
                if (PACKED) { B0[j] = wp[(kt * 16 + w * 2 + 0) * 64 + lane];
                              B1[j] = wp[(kt * 16 + w * 2 + 1) * 64 + lane]; }
                else        { B0[j] = load_bfrag(wx2, 256, kt, w * 2 + 0, lane);
                              B1[j] = load_bfrag(wx2, 256, kt, w * 2 + 1, lane); }
            }
#pragma unroll
            for (int j = 0; j < 4; j++) {
                acc[0] = __builtin_amdgcn_mfma_f32_16x16x32_bf16(A[kb * 4 + j], B0[j], acc[0], 0, 0, 0);
                acc[1] = __builtin_amdgcn_mfma_f32_16x16x32_bf16(A[kb * 4 + j], B1[j], acc[1], 0, 0, 0);
            }
        }
        // X2[m'][i=ntE][j=cl]; dest lane' = (j>>3)*16 + i, jj = j&7
#pragma unroll
        for (int q = 0; q < 2; q++) {
            int ntE = w * 2 + q;
            int lp  = (cl >> 3) * 16 + ntE;
            int jj  = cl & 7;
#pragma unroll
            for (int r = 0; r < 4; r++) {
                int m = hh * 4 + r;
                s_x2f[(m * 32 + lp) * 8 + jj] = f2bf(acc[q][r]);
            }
        }
    }
    __syncthreads();

    // ---- Phase F: fts_X via MFMA (zero-padded K=16) + depthwise via butterfly ----
    // waves 0..3: h2 half (channels 0..63, B-frags from LDS)
    // waves 4..7: fts half (channels 64..127, packed from global, depth-3 prefetch)
    {
        const int  cH    = (w & 3) * 16 + cl;     // 0..63 within half
        const bool isF   = (w >= 4);
        const int  cFull = isF ? (64 + cH) : cH;
        float wd[16];
#pragma unroll
        for (int d = 0; d < 4; d++) {
            float4 v = *(const float4*)&wdw[cFull * 64 + d * 16 + 4 * hh];
            wd[d * 4 + 0] = v.x; wd[d * 4 + 1] = v.y;
            wd[d * 4 + 2] = v.z; wd[d * 4 + 3] = v.w;
        }
        float4 bd = *(const float4*)&bdw[cFull * 4];
        const float* ftsp = fts + (size_t)gp0 * 1024 + cH;

        float f0[8], f1[8], f2[8], f3[8];
        auto LDF = [&](int m, float* f) {
            if (isF && lane < 32) {
                const float* p = ftsp + (m * 16 + hh * 8) * 64;
#pragma unroll
                for (int j = 0; j < 8; j++) f[j] = p[j * 64];
            }
        };
        auto STEP = [&](int m, float* fc_, float* fl_) {
            if (m + 3 < 16) LDF(m + 3, fl_);    // depth-3 prefetch
            bf16x8 a = {};
            if (lane < 32) a = *(const bf16x8*)&s_x2f[(m * 32 + lane) * 8];
            bf16x8 b = {};
            if (isF) {
                if (lane < 32) {
                    union { bf16x8 v; uint4 u; } ub;
                    ub.u = make_uint4(pk2(fc_[0], fc_[1]), pk2(fc_[2], fc_[3]),
                                      pk2(fc_[4], fc_[5]), pk2(fc_[6], fc_[7]));
                    b = ub.v;
                }
            } else {
                if (lane < 32) b = *(const bf16x8*)&s_h2f[((m * 4 + (w & 3)) * 32 + lane) * 8];
            }
            f32x4 acc = {0.f, 0.f, 0.f, 0.f};
            acc = __builtin_amdgcn_mfma_f32_16x16x32_bf16(a, b, acc, 0, 0, 0);
            // depthwise: rows i = 4*hh + r live in this lane; reduce across hh groups
            float o[4];
#pragma unroll
            for (int d = 0; d < 4; d++) {
                float s = acc[0] * wd[d * 4 + 0];
                s = fmaf(acc[1], wd[d * 4 + 1], s);
                s = fmaf(acc[2], wd[d * 4 + 2], s);
                s = fmaf(acc[3], wd[d * 4 + 3], s);
                s += __shfl_xor(s, 16);
                s += __shfl_xor(s, 32);
                o[d] = s;
            }
            if (hh == 0) {
                ushort4 v;
                v.x = f2bf(o[0] + bd.x); v.y = f2bf(o[1] + bd.y);
                v.z = f2bf(o[2] + bd.z); v.w = f2bf(o[3] + bd.w);
                *(ushort4*)&s_dw[m * 520 + cFull * 4] = v;
            }
        };
        LDF(0, f0); LDF(1, f1); LDF(2, f2);
#pragma unroll
        for (int q = 0; q < 4; q++) {
            STEP(4 * q + 0, f0, f3);
            STEP(4 * q + 1, f1, f0);
            STEP(4 * q + 2, f2, f1);
            STEP(4 * q + 3, f3, f2);
        }
    }
    __syncthreads();

    // ---- Phase G: y = BN(elu(dw @ wpw + bpw)), MFMA M=16,N=128,K=512; 1 nt/wave ----
    // Batched: two rounds of A[8]+B[8].
    {
        const bf16x8* wp = (const bf16x8*)wpack + 16896;  // wpw
        float bv = bpw[w * 16 + cl];
        f32x4 acc = {bv, bv, bv, bv};
#pragma unroll
        for (int kb = 0; kb < 2; kb++) {
            bf16x8 A[8], B[8];
#pragma unroll
            for (int j = 0; j < 8; j++) {
                int kt = kb * 8 + j;
                if (PACKED) B[j] = wp[(kt * 8 + w) * 64 + lane];
                else        B[j] = load_bfrag(wpw, 128, kt, w, lane);
                A[j] = *(const bf16x8*)&s_dw[cl * 520 + kt * 32 + hh * 8];
            }
#pragma unroll
            for (int j = 0; j < 8; j++)
                acc = __builtin_amdgcn_mfma_f32_16x16x32_bf16(A[j], B[j], acc, 0, 0, 0);
        }
        int co = w * 16 + cl;
        float scale = bn_gamma[co] * rsqrtf(bn_var[co] + 1e-5f);
        float shift = bn_beta[co] - bn_mean[co] * scale;
#pragma unroll
        for (int r = 0; r < 4; r++) {
            int m = hh * 4 + r;
            out[(gp0 + m) * 128 + co] = fmaf(elu_f(acc[r]), scale, shift);
        }
    }
}

extern "C" void kernel_launch(void* const* d_in, const int* in_sizes, int n_in,
                              void* d_out, int out_size, void* d_ws, size_t ws_size,
                              hipStream_t stream) {
    const float* rep_pt   = (const float*)d_in[0];
    const float* pts      = (const float*)d_in[1];
    const float* fts      = (const float*)d_in[2];
    const float* w1       = (const float*)d_in[3];
    const float* b1       = (const float*)d_in[4];
    const float* w2       = (const float*)d_in[5];
    const float* b2       = (const float*)d_in[6];
    const float* wc1      = (const float*)d_in[7];
    const float* bc1      = (const float*)d_in[8];
    const float* wx1      = (const float*)d_in[9];
    const float* bx1      = (const float*)d_in[10];
    const float* wx2      = (const float*)d_in[11];
    const float* bx2      = (const float*)d_in[12];
    const float* wdw      = (const float*)d_in[13];
    const float* bdw      = (const float*)d_in[14];
    const float* wpw      = (const float*)d_in[15];
    const float* bpw      = (const float*)d_in[16];
    const float* bn_gamma = (const float*)d_in[17];
    const float* bn_beta  = (const float*)d_in[18];
    const float* bn_mean  = (const float*)d_in[19];
    const float* bn_var   = (const float*)d_in[20];
    float* out = (float*)d_out;

    const bool packed = (d_ws != nullptr) && (ws_size >= (size_t)WS_NEEDED);
    unsigned short* wpack = (unsigned short*)d_ws;

    if (packed) {
        pack_weights<<<98, 256, 0, stream>>>(w2, wx1, wx2, wpw, wpack);
        xconv_main<true><<<NPTS / MPB, NTHR, 0, stream>>>(
            rep_pt, pts, fts, w1, b1, w2, b2, wc1, bc1, wx1, bx1, wx2, bx2,
            wdw, bdw, wpw, bpw, bn_gamma, bn_beta, bn_mean, bn_var, wpack, out);
    } else {
        xconv_main<false><<<NPTS / MPB, NTHR, 0, stream>>>(
            rep_pt, pts, fts, w1, b1, w2, b2, wc1, bc1, wx1, bx1, wx2, bx2,
            wdw, bdw, wpw, bpw, bn_gamma, bn_beta, bn_mean, bn_var, (const unsigned short*)nullptr, out);
    }
}

// Round 8
// 180.226 us; speedup vs baseline: 1.3042x; 1.0307x over previous
//
#include <hip/hip_runtime.h>

#define NPTS 16384
#define MPB  16
#define NTHR 512
#define WS_NEEDED 434176u   // 424 frags * 1KB (392 prior + 32 wc1)

typedef __attribute__((ext_vector_type(8))) short bf16x8;
typedef __attribute__((ext_vector_type(4))) float f32x4;

__device__ __forceinline__ unsigned short f2bf(float x) {
    unsigned u = __float_as_uint(x);
    return (unsigned short)((u + 0x7FFFu + ((u >> 16) & 1u)) >> 16);
}
__device__ __forceinline__ unsigned pk2(float a, float b) {
    return (unsigned)f2bf(a) | ((unsigned)f2bf(b) << 16);
}
__device__ __forceinline__ float bf2f(unsigned short h) {
    return __uint_as_float(((unsigned)h) << 16);
}
__device__ __forceinline__ float elu_f(float x) {
    return x > 0.f ? x : (__expf(x) - 1.f);
}

// Gather one 16x16x32 B-fragment directly from a row-major fp32 matrix W[K][N].
__device__ __forceinline__ bf16x8 load_bfrag(const float* __restrict__ W, int N,
                                             int kt, int nt, int lane) {
    int k0  = kt * 32 + ((lane >> 4) << 3);
    int col = nt * 16 + (lane & 15);
    const float* s = W + k0 * N + col;
    bf16x8 r;
#pragma unroll
    for (int j = 0; j < 8; j++) r[j] = (short)f2bf(s[j * N]);
    return r;
}

// ---------------- prep: pack w2/wx1/wx2/wpw/wc1 into bf16 B-fragments ----
// frag order: w2 [kt*4+nt] (8), wx1 (128), wx2 (128), wpw (128),
//             wc1 [kt*16+nt] (32, K=48 zero-padded to 64; B[f][o]=wc1[o][f%3][f/3])
__global__ void pack_weights(const float* __restrict__ w2,
                             const float* __restrict__ wx1,
                             const float* __restrict__ wx2,
                             const float* __restrict__ wpw,
                             const float* __restrict__ wc1,
                             unsigned short* __restrict__ dst) {
    int gid  = blockIdx.x * 256 + threadIdx.x;   // 106*256 = 27136 = 424*64
    int frag = gid >> 6, lane = gid & 63;
    unsigned v[4];
    if (frag >= 392) {                            // wc1 frags
        int fl = frag - 392, kt = fl >> 4, nt = fl & 15;
        int col = nt * 16 + (lane & 15);
#pragma unroll
        for (int u = 0; u < 4; u++) {
            int f0 = kt * 32 + (lane >> 4) * 8 + 2 * u;
            float a = (f0     < 48) ? wc1[col * 48 + (f0 % 3) * 16 + (f0 / 3)] : 0.f;
            float b = (f0 + 1 < 48) ? wc1[col * 48 + ((f0 + 1) % 3) * 16 + ((f0 + 1) / 3)] : 0.f;
            v[u] = pk2(a, b);
        }
        *(uint4*)&dst[gid * 8] = make_uint4(v[0], v[1], v[2], v[3]);
        return;
    }
    const float* src; int N, fl;
    if      (frag <   8) { src = w2;  N =  64; fl = frag;       }
    else if (frag < 136) { src = wx1; N = 256; fl = frag - 8;   }
    else if (frag < 264) { src = wx2; N = 256; fl = frag - 136; }
    else                 { src = wpw; N = 128; fl = frag - 264; }
    int NT  = N >> 4;
    int kt  = fl / NT, nt = fl - kt * NT;
    int k0  = kt * 32 + (lane >> 4) * 8;
    int col = nt * 16 + (lane & 15);
    const float* s = src + k0 * N + col;
#pragma unroll
    for (int u = 0; u < 4; u++) {
        unsigned lo = f2bf(s[(2 * u) * N]);
        unsigned hi = f2bf(s[(2 * u + 1) * N]);
        v[u] = lo | (hi << 16);
    }
    *(uint4*)&dst[gid * 8] = make_uint4(v[0], v[1], v[2], v[3]);
}

// ---------------- main fused kernel -----------------------------------------
// MPB=16, 512 threads (8 waves), LDS 60928 B -> 2 blocks/CU.
// 5 barriers: A | slot1{X0-MFMA then h2, all waves} | D | E | F | G
// r8: X0 via MFMA (split-precision A: hi+lo bf16 of f32 ptsl, so accuracy ~
// matches the old f32 VALU path); F depthwise uses 3-shfl reduce-scatter.
// LDS map:
//   0     s_ptsl [16][48] f32                 3072
//   3072  s_h2f  [16 m][4 nt][32 lane][8] u16 32768  (B-frag layout, slot1..F)
//   35840 overlay region 25088:
//         s_x0  [16][264] u16  8448   (slot1->D) @35840
//         s_x2f [16][32][8] u16 8192  (E->F)     @35840
//         s_x1  [16][264] u16  8448   (D->E)     @44288
//         s_dw  [16][520] u16 16640   (F->G)     @44288
template <bool PACKED>
__global__ __launch_bounds__(NTHR, 2)
void xconv_main(const float* __restrict__ rep_pt, const float* __restrict__ pts,
                const float* __restrict__ fts,
                const float* __restrict__ w1,  const float* __restrict__ b1,
                const float* __restrict__ w2,  const float* __restrict__ b2,
                const float* __restrict__ wc1, const float* __restrict__ bc1,
                const float* __restrict__ wx1, const float* __restrict__ bx1,
                const float* __restrict__ wx2, const float* __restrict__ bx2,
                const float* __restrict__ wdw, const float* __restrict__ bdw,
                const float* __restrict__ wpw, const float* __restrict__ bpw,
                const float* __restrict__ bn_gamma, const float* __restrict__ bn_beta,
                const float* __restrict__ bn_mean,  const float* __restrict__ bn_var,
                const unsigned short* __restrict__ wpack,
                float* __restrict__ out) {
    __shared__ __align__(16) char smem[60928];
    float*          s_ptsl = (float*)smem;                          // [16][48]
    unsigned short* s_h2f  = (unsigned short*)(smem + 3072);        // [16][4][32][8]
    unsigned short* s_x0   = (unsigned short*)(smem + 35840);       // [16][264]
    unsigned short* s_x2f  = (unsigned short*)(smem + 35840);       // [16][32][8]
    unsigned short* s_x1   = (unsigned short*)(smem + 44288);       // [16][264]
    unsigned short* s_dw   = (unsigned short*)(smem + 44288);       // [16][520]

    const int t    = threadIdx.x;
    const int lane = t & 63;
    const int w    = t >> 6;          // 0..7
    const int cl   = lane & 15;
    const int hh   = lane >> 4;
    const int gp0  = blockIdx.x * MPB;

    // ---- Phase A: pts_local -> LDS ----
    for (int idx = t; idx < MPB * 48; idx += NTHR) {
        int m = idx / 48, r = idx - m * 48;
        int k = r / 3,    d = r - k * 3;
        int gp = gp0 + m;
        s_ptsl[idx] = pts[(gp * 16 + k) * 3 + d] - rep_pt[gp * 3 + d];
    }
    __syncthreads();

    // ---- SLOT1a: X0 = elu(ptsl @ wc1^T + bc1) via MFMA, M=16,N=256,K=48(pad64)
    // split-precision A (hi+lo) keeps f32-grade accuracy. All 8 waves, 2 nt each.
    {
        const bf16x8* wpc = (const bf16x8*)wpack + 25088;   // wc1 frags (392*64)
        const float* pr = &s_ptsl[cl * 48];
        bf16x8 A0h, A0l, A1h, A1l;
        {
            unsigned vh[4], vl[4];
#pragma unroll
            for (int u = 0; u < 4; u++) {
                float a = pr[hh * 8 + 2 * u], b = pr[hh * 8 + 2 * u + 1];
                unsigned short ah = f2bf(a), bh = f2bf(b);
                vh[u] = (unsigned)ah | ((unsigned)bh << 16);
                vl[u] = pk2(a - bf2f(ah), b - bf2f(bh));
            }
            union { bf16x8 b8; uint4 u4; } ua;
            ua.u4 = make_uint4(vh[0], vh[1], vh[2], vh[3]); A0h = ua.b8;
            ua.u4 = make_uint4(vl[0], vl[1], vl[2], vl[3]); A0l = ua.b8;
            if (hh < 2) {
#pragma unroll
                for (int u = 0; u < 4; u++) {
                    float a = pr[32 + hh * 8 + 2 * u], b = pr[32 + hh * 8 + 2 * u + 1];
                    unsigned short ah = f2bf(a), bh = f2bf(b);
                    vh[u] = (unsigned)ah | ((unsigned)bh << 16);
                    vl[u] = pk2(a - bf2f(ah), b - bf2f(bh));
                }
            } else {
#pragma unroll
                for (int u = 0; u < 4; u++) { vh[u] = 0u; vl[u] = 0u; }
            }
            ua.u4 = make_uint4(vh[0], vh[1], vh[2], vh[3]); A1h = ua.b8;
            ua.u4 = make_uint4(vl[0], vl[1], vl[2], vl[3]); A1l = ua.b8;
        }
        auto ld_wc1 = [&](int kt, int nt) -> bf16x8 {
            bf16x8 r;
#pragma unroll
            for (int j = 0; j < 8; j++) {
                int f = kt * 32 + hh * 8 + j;
                int col = nt * 16 + cl;
                r[j] = (f < 48) ? (short)f2bf(wc1[col * 48 + (f % 3) * 16 + (f / 3)]) : (short)0;
            }
            return r;
        };
#pragma unroll
        for (int q = 0; q < 2; q++) {
            int nt = w * 2 + q;
            bf16x8 B0, B1;
            if (PACKED) { B0 = wpc[(0 * 16 + nt) * 64 + lane]; B1 = wpc[(1 * 16 + nt) * 64 + lane]; }
            else        { B0 = ld_wc1(0, nt);                  B1 = ld_wc1(1, nt); }
            float bv = bc1[nt * 16 + cl];
            f32x4 acc = {bv, bv, bv, bv};
            acc = __builtin_amdgcn_mfma_f32_16x16x32_bf16(A0l, B0, acc, 0, 0, 0);
            acc = __builtin_amdgcn_mfma_f32_16x16x32_bf16(A1l, B1, acc, 0, 0, 0);
            acc = __builtin_amdgcn_mfma_f32_16x16x32_bf16(A0h, B0, acc, 0, 0, 0);
            acc = __builtin_amdgcn_mfma_f32_16x16x32_bf16(A1h, B1, acc, 0, 0, 0);
#pragma unroll
            for (int r = 0; r < 4; r++) {
                int m = hh * 4 + r;
                s_x0[m * 264 + nt * 16 + cl] = f2bf(elu_f(acc[r]));
            }
        }
    }

    // ---- SLOT1b: h1-in-register + h2 MFMA -> s_h2f. All 8 waves, 2 tiles each.
    {
        const bf16x8* wp = (const bf16x8*)wpack;   // w2 frags at base 0
        float w1s[2][3][8], b1s[2][8];
#pragma unroll
        for (int kt = 0; kt < 2; kt++) {
#pragma unroll
            for (int d = 0; d < 3; d++)
#pragma unroll
                for (int j = 0; j < 8; j++)
                    w1s[kt][d][j] = w1[d * 64 + kt * 32 + hh * 8 + j];
#pragma unroll
            for (int j = 0; j < 8; j++) b1s[kt][j] = b1[kt * 32 + hh * 8 + j];
        }
        bf16x8 af[2][2];
#pragma unroll
        for (int i = 0; i < 2; i++) {
            int tile = w * 2 + i;             // point index 0..15
            float p0 = s_ptsl[tile * 48 + cl * 3 + 0];
            float p1 = s_ptsl[tile * 48 + cl * 3 + 1];
            float p2 = s_ptsl[tile * 48 + cl * 3 + 2];
#pragma unroll
            for (int kt = 0; kt < 2; kt++) {
                unsigned v[4];
#pragma unroll
                for (int u = 0; u < 4; u++) {
                    int j0 = 2 * u, j1 = 2 * u + 1;
                    float ha = elu_f(fmaf(p0, w1s[kt][0][j0],
                                     fmaf(p1, w1s[kt][1][j0],
                                     fmaf(p2, w1s[kt][2][j0], b1s[kt][j0]))));
                    float hb = elu_f(fmaf(p0, w1s[kt][0][j1],
                                     fmaf(p1, w1s[kt][1][j1],
                                     fmaf(p2, w1s[kt][2][j1], b1s[kt][j1]))));
                    v[u] = pk2(ha, hb);
                }
                union { bf16x8 b8; uint4 u4; } ua;
                ua.u4 = make_uint4(v[0], v[1], v[2], v[3]);
                af[i][kt] = ua.b8;
            }
        }
        float bias[4];
#pragma unroll
        for (int nt = 0; nt < 4; nt++) bias[nt] = b2[nt * 16 + cl];
#pragma unroll
        for (int nt = 0; nt < 4; nt++) {
            bf16x8 bA, bB;
            if (PACKED) { bA = wp[(0 * 4 + nt) * 64 + lane]; bB = wp[(1 * 4 + nt) * 64 + lane]; }
            else        { bA = load_bfrag(w2, 64, 0, nt, lane); bB = load_bfrag(w2, 64, 1, nt, lane); }
#pragma unroll
            for (int i = 0; i < 2; i++) {
                int tile = w * 2 + i;
                f32x4 acc = {bias[nt], bias[nt], bias[nt], bias[nt]};
                acc = __builtin_amdgcn_mfma_f32_16x16x32_bf16(af[i][0], bA, acc, 0, 0, 0);
                acc = __builtin_amdgcn_mfma_f32_16x16x32_bf16(af[i][1], bB, acc, 0, 0, 0);
                // scatter to B-frag layout: k = 4*hh + r, lane' = (k>>3)*16+cl, j = k&7
                unsigned lo = pk2(elu_f(acc[0]), elu_f(acc[1]));
                unsigned hi = pk2(elu_f(acc[2]), elu_f(acc[3]));
                unsigned short* dp = &s_h2f[(((tile * 4 + nt) * 32) + (hh >> 1) * 16 + cl) * 8 + (hh & 1) * 4];
                *(uint2*)dp = make_uint2(lo, hi);
            }
        }
    }
    __syncthreads();

    // ---- Phase D: X1 = elu(X0 @ wx1 + bx1), MFMA M=16,N=256,K=256; 2 nt/wave ----
    {
        const bf16x8* wp = (const bf16x8*)wpack + 512;  // wx1
        bf16x8 A[8];
#pragma unroll
        for (int kt = 0; kt < 8; kt++)
            A[kt] = *(const bf16x8*)&s_x0[cl * 264 + kt * 32 + hh * 8];
        f32x4 acc[2];
#pragma unroll
        for (int q = 0; q < 2; q++) {
            float bv = bx1[(w * 2 + q) * 16 + cl];
            acc[q] = (f32x4){bv, bv, bv, bv};
        }
#pragma unroll
        for (int kb = 0; kb < 2; kb++) {
            bf16x8 B0[4], B1[4];
#pragma unroll
            for (int j = 0; j < 4; j++) {
                int kt = kb * 4 + j;
                if (PACKED) { B0[j] = wp[(kt * 16 + w * 2 + 0) * 64 + lane];
                              B1[j] = wp[(kt * 16 + w * 2 + 1) * 64 + lane]; }
                else        { B0[j] = load_bfrag(wx1, 256, kt, w * 2 + 0, lane);
                              B1[j] = load_bfrag(wx1, 256, kt, w * 2 + 1, lane); }
            }
#pragma unroll
            for (int j = 0; j < 4; j++) {
                acc[0] = __builtin_amdgcn_mfma_f32_16x16x32_bf16(A[kb * 4 + j], B0[j], acc[0], 0, 0, 0);
                acc[1] = __builtin_amdgcn_mfma_f32_16x16x32_bf16(A[kb * 4 + j], B1[j], acc[1], 0, 0, 0);
            }
        }
#pragma unroll
        for (int q = 0; q < 2; q++) {
            int nt = w * 2 + q;
#pragma unroll
            for (int r = 0; r < 4; r++) {
                int m = hh * 4 + r;
                s_x1[m * 264 + nt * 16 + cl] = f2bf(elu_f(acc[q][r]));
            }
        }
    }
    __syncthreads();

    // ---- Phase E: X2 = X1 @ wx2 + bx2 (no act), MFMA; scatter to A-frag layout ----
    {
        const bf16x8* wp = (const bf16x8*)wpack + 8704;  // wx2
        bf16x8 A[8];
#pragma unroll
        for (int kt = 0; kt < 8; kt++)
            A[kt] = *(const bf16x8*)&s_x1[cl * 264 + kt * 32 + hh * 8];
        f32x4 acc[2];
#pragma unroll
        for (int q = 0; q < 2; q++) {
            float bv = bx2[(w * 2 + q) * 16 + cl];
            acc[q] = (f32x4){bv, bv, bv, bv};
        }
#pragma unroll
        for (int kb = 0; kb < 2; kb++) {
            bf16x8 B0[4], B1[4];
#pragma unroll
            for (int j = 0; j < 4; j++) {
                int kt = kb * 4 + j;
                if (PACKED) { B0[j] = wp[(kt * 16 + w * 2 + 0) * 64 + lane];
                              B1[j] = wp[(kt * 16 + w * 2 + 1) * 64 + lane]; }
                else        { B0[j] = load_bfrag(wx2, 256, kt, w * 2 + 0, lane);
                              B1[j] = load_bfrag(wx2, 256, kt, w * 2 + 1, lane); }
            }
#pragma unroll
            for (int j = 0; j < 4; j++) {
                acc[0] = __builtin_amdgcn_mfma_f32_16x16x32_bf16(A[kb * 4 + j], B0[j], acc[0], 0, 0, 0);
                acc[1] = __builtin_amdgcn_mfma_f32_16x16x32_bf16(A[kb * 4 + j], B1[j], acc[1], 0, 0, 0);
            }
        }
        // X2[m'][i=ntE][j=cl]; dest lane' = (j>>3)*16 + i, jj = j&7
#pragma unroll
        for (int q = 0; q < 2; q++) {
            int ntE = w * 2 + q;
            int lp  = (cl >> 3) * 16 + ntE;
            int jj  = cl & 7;
#pragma unroll
            for (int r = 0; r < 4; r++) {
                int m = hh * 4 + r;
                s_x2f[(m * 32 + lp) * 8 + jj] = f2bf(acc[q][r]);
            }
        }
    }
    __syncthreads();

    // ---- Phase F: fts_X via MFMA (zero-padded K=16) + depthwise reduce-scatter ----
    // waves 0..3: h2 half (channels 0..63, B-frags from LDS)
    // waves 4..7: fts half (channels 64..127, packed from global, depth-3 prefetch)
    {
        const int  cH    = (w & 3) * 16 + cl;     // 0..63 within half
        const bool isF   = (w >= 4);
        const int  cFull = isF ? (64 + cH) : cH;
        const int  o1    = hh & 1, o2 = (hh >> 1) & 1;
        const int  dfin  = o1 * 2 + o2;           // this lane's output depth index
        float wd[16];
#pragma unroll
        for (int d = 0; d < 4; d++) {
            float4 v = *(const float4*)&wdw[cFull * 64 + d * 16 + 4 * hh];
            wd[d * 4 + 0] = v.x; wd[d * 4 + 1] = v.y;
            wd[d * 4 + 2] = v.z; wd[d * 4 + 3] = v.w;
        }
        float bdl = bdw[cFull * 4 + dfin];
        const float* ftsp = fts + (size_t)gp0 * 1024 + cH;

        float f0[8], f1[8], f2[8], f3[8];
        auto LDF = [&](int m, float* f) {
            if (isF && lane < 32) {
                const float* p = ftsp + (m * 16 + hh * 8) * 64;
#pragma unroll
                for (int j = 0; j < 8; j++) f[j] = p[j * 64];
            }
        };
        auto STEP = [&](int m, float* fc_, float* fl_) {
            if (m + 3 < 16) LDF(m + 3, fl_);    // depth-3 prefetch
            bf16x8 a = {};
            if (lane < 32) a = *(const bf16x8*)&s_x2f[(m * 32 + lane) * 8];
            bf16x8 b = {};
            if (isF) {
                if (lane < 32) {
                    union { bf16x8 v; uint4 u; } ub;
                    ub.u = make_uint4(pk2(fc_[0], fc_[1]), pk2(fc_[2], fc_[3]),
                                      pk2(fc_[4], fc_[5]), pk2(fc_[6], fc_[7]));
                    b = ub.v;
                }
            } else {
                if (lane < 32) b = *(const bf16x8*)&s_h2f[((m * 4 + (w & 3)) * 32 + lane) * 8];
            }
            f32x4 acc = {0.f, 0.f, 0.f, 0.f};
            acc = __builtin_amdgcn_mfma_f32_16x16x32_bf16(a, b, acc, 0, 0, 0);
            // lane holds fts_X rows 4*hh+r for col c=cl; partials for all 4 d:
            float p[4];
#pragma unroll
            for (int d = 0; d < 4; d++) {
                float s = acc[0] * wd[d * 4 + 0];
                s = fmaf(acc[1], wd[d * 4 + 1], s);
                s = fmaf(acc[2], wd[d * 4 + 2], s);
                s = fmaf(acc[3], wd[d * 4 + 3], s);
                p[d] = s;
            }
            // reduce-scatter across hh: stage1 xor16 keeps d-pair, stage2 xor32 keeps one d
            float u  = o1 ? p[0] : p[2];
            float v  = o1 ? p[1] : p[3];
            float us = __shfl_xor(u, 16);
            float vs = __shfl_xor(v, 16);
            float s0 = (o1 ? p[2] : p[0]) + us;   // d = o1*2
            float s1 = (o1 ? p[3] : p[1]) + vs;   // d = o1*2 + 1
            float x  = o2 ? s0 : s1;
            float xs = __shfl_xor(x, 32);
            float dv = (o2 ? s1 : s0) + xs;       // full sum for d = dfin
            s_dw[m * 520 + cFull * 4 + dfin] = f2bf(dv + bdl);
        };
        LDF(0, f0); LDF(1, f1); LDF(2, f2);
#pragma unroll
        for (int q = 0; q < 4; q++) {
            STEP(4 * q + 0, f0, f3);
            STEP(4 * q + 1, f1, f0);
            STEP(4 * q + 2, f2, f1);
            STEP(4 * q + 3, f3, f2);
        }
    }
    __syncthreads();

    // ---- Phase G: y = BN(elu(dw @ wpw + bpw)), MFMA M=16,N=128,K=512; 1 nt/wave ----
    {
        const bf16x8* wp = (const bf16x8*)wpack + 16896;  // wpw
        float bv = bpw[w * 16 + cl];
        f32x4 acc = {bv, bv, bv, bv};
#pragma unroll
        for (int kb = 0; kb < 2; kb++) {
            bf16x8 A[8], B[8];
#pragma unroll
            for (int j = 0; j < 8; j++) {
                int kt = kb * 8 + j;
                if (PACKED) B[j] = wp[(kt * 8 + w) * 64 + lane];
                else        B[j] = load_bfrag(wpw, 128, kt, w, lane);
                A[j] = *(const bf16x8*)&s_dw[cl * 520 + kt * 32 + hh * 8];
            }
#pragma unroll
            for (int j = 0; j < 8; j++)
                acc = __builtin_amdgcn_mfma_f32_16x16x32_bf16(A[j], B[j], acc, 0, 0, 0);
        }
        int co = w * 16 + cl;
        float scale = bn_gamma[co] * rsqrtf(bn_var[co] + 1e-5f);
        float shift = bn_beta[co] - bn_mean[co] * scale;
#pragma unroll
        for (int r = 0; r < 4; r++) {
            int m = hh * 4 + r;
            out[(gp0 + m) * 128 + co] = fmaf(elu_f(acc[r]), scale, shift);
        }
    }
}

extern "C" void kernel_launch(void* const* d_in, const int* in_sizes, int n_in,
                              void* d_out, int out_size, void* d_ws, size_t ws_size,
                              hipStream_t stream) {
    const float* rep_pt   = (const float*)d_in[0];
    const float* pts      = (const float*)d_in[1];
    const float* fts      = (const float*)d_in[2];
    const float* w1       = (const float*)d_in[3];
    const float* b1       = (const float*)d_in[4];
    const float* w2       = (const float*)d_in[5];
    const float* b2       = (const float*)d_in[6];
    const float* wc1      = (const float*)d_in[7];
    const float* bc1      = (const float*)d_in[8];
    const float* wx1      = (const float*)d_in[9];
    const float* bx1      = (const float*)d_in[10];
    const float* wx2      = (const float*)d_in[11];
    const float* bx2      = (const float*)d_in[12];
    const float* wdw      = (const float*)d_in[13];
    const float* bdw      = (const float*)d_in[14];
    const float* wpw      = (const float*)d_in[15];
    const float* bpw      = (const float*)d_in[16];
    const float* bn_gamma = (const float*)d_in[17];
    const float* bn_beta  = (const float*)d_in[18];
    const float* bn_mean  = (const float*)d_in[19];
    const float* bn_var   = (const float*)d_in[20];
    float* out = (float*)d_out;

    const bool packed = (d_ws != nullptr) && (ws_size >= (size_t)WS_NEEDED);
    unsigned short* wpack = (unsigned short*)d_ws;

    if (packed) {
        pack_weights<<<106, 256, 0, stream>>>(w2, wx1, wx2, wpw, wc1, wpack);
        xconv_main<true><<<NPTS / MPB, NTHR, 0, stream>>>(
            rep_pt, pts, fts, w1, b1, w2, b2, wc1, bc1, wx1, bx1, wx2, bx2,
            wdw, bdw, wpw, bpw, bn_gamma, bn_beta, bn_mean, bn_var, wpack, out);
    } else {
        xconv_main<false><<<NPTS / MPB, NTHR, 0, stream>>>(
            rep_pt, pts, fts, w1, b1, w2, b2, wc1, bc1, wx1, bx1, wx2, bx2,
            wdw, bdw, wpw, bpw, bn_gamma, bn_beta, bn_mean, bn_var, (const unsigned short*)nullptr, out);
    }
}